// Round 11
// baseline (285.214 us; speedup 1.0000x reference)
//
#include <hip/hip_runtime.h>
#include <hip/hip_bf16.h>
#include <math.h>

// Problem constants
#define BB 8
#define NN_ 128
#define DD 256
#define LL 64
#define EH 64
#define NG 3

typedef __attribute__((ext_vector_type(8))) short bs8;   // 8 bf16 (4 VGPR)
typedef __attribute__((ext_vector_type(4))) float f4;    // 4 f32

__device__ __forceinline__ short f2bf(float f) {
    __hip_bfloat16 h = __float2bfloat16(f);
    return *reinterpret_cast<short*>(&h);
}

__device__ __forceinline__ bs8 cvt8(const float* __restrict__ p) {
    bs8 r;
    #pragma unroll
    for (int i = 0; i < 8; ++i) r[i] = f2bf(p[i]);
    return r;
}

__device__ __forceinline__ float blockReduceSum(float v, float* sRed) {
    int tid = threadIdx.x;
    __syncthreads();
    sRed[tid] = v;
    __syncthreads();
    for (int s = 128; s > 0; s >>= 1) {
        if (tid < s) sRed[tid] += sRed[tid + s];
        __syncthreads();
    }
    return sRed[0];
}

// ---------------- unified prep (unchanged from r10) ----------------
// blocks 0..143 uw1^T, 144..191 uw2^T, 192..203 gw2^T, 204..215 gw1[:256]^T,
// 216..231 kw^T, 232 adj-probe+wsum, 233..488 layer-cost conv+GEMM,
// 489..552 nodeproj + composite layer-0 pregate
__global__ __launch_bounds__(256) void k_prep(
    const float* __restrict__ uw1, const float* __restrict__ uw2,
    const float* __restrict__ gw2, const float* __restrict__ gw1,
    const float* __restrict__ kw, const unsigned char* __restrict__ adj,
    const float* __restrict__ lc, const float* __restrict__ cw,
    const float* __restrict__ cb, const float* __restrict__ lpw,
    const float* __restrict__ nf, const float* __restrict__ pnw,
    const float* __restrict__ pnb, const float* __restrict__ gb1,
    unsigned short* __restrict__ w1t, unsigned short* __restrict__ w2t,
    unsigned short* __restrict__ g2t, unsigned short* __restrict__ g1t,
    unsigned short* __restrict__ kwt, int* __restrict__ mode,
    float* __restrict__ lpart, float* __restrict__ wsum,
    float* __restrict__ h, float* __restrict__ preg)
{
    const int blk = blockIdx.x, tid = threadIdx.x;
    if (blk == 232) {   // adj dtype probe + wsum
        __shared__ int sOff, sBig;
        __shared__ float sRedD[256];
        if (tid == 0) { sOff = 0; sBig = 0; }
        __syncthreads();
        int off = 0, big = 0;
        #pragma unroll
        for (int k = 0; k < 4; ++k) {
            unsigned char v = adj[tid * 4 + k];
            if (v > 1) big = 1;
            if (k != 0 && v != 0) off = 1;
        }
        if (off) atomicOr(&sOff, 1);
        if (big) atomicOr(&sBig, 1);
        __syncthreads();
        if (tid == 0) mode[0] = sBig ? 2 : (sOff ? 0 : 1);
        for (int bb = 0; bb < 8; ++bb) {
            float v = 0.f;
            if (tid < 128) {
                const float* p = nf + (size_t)(bb * 128 + tid) * 11;
                v = p[0] * p[7];
            }
            float s = blockReduceSum(v, sRedD);
            if (tid == 0) wsum[bb] = s;
        }
        return;
    }
    if (blk >= 489) {   // nodeproj + composite layer-0 pregate (16 rows)
        const int row0 = (blk - 489) * 16;
        __shared__ float sF[16][12];
        __shared__ float sCW[12][64];
        if (tid < 176) sF[tid / 11][tid % 11] = nf[(size_t)(row0 + tid / 11) * 11 + tid % 11];
        {
            const int t = tid & 63, f0 = tid >> 6;
            const float* r0p = pnw + (size_t)f0 * DD;
            const float* r1p = pnw + (size_t)(f0 + 4) * DD;
            const float* r2p = (f0 + 8 < 11) ? (pnw + (size_t)(f0 + 8) * DD) : pnb;
            float a0 = 0.f, a1 = 0.f, a2 = 0.f;
            for (int k = 0; k < 256; ++k) {
                float g = gw1[k * EH + t];
                a0 += r0p[k] * g; a1 += r1p[k] * g; a2 += r2p[k] * g;
            }
            if (f0 + 8 == 11) a2 += gb1[t];
            sCW[f0][t] = a0; sCW[f0 + 4][t] = a1; sCW[f0 + 8][t] = a2;
        }
        __syncthreads();
        float acc[16];
        {
            float bb = pnb[tid];
            #pragma unroll
            for (int rr = 0; rr < 16; ++rr) acc[rr] = bb;
        }
        #pragma unroll
        for (int f = 0; f < 11; ++f) {
            float wf = pnw[f * DD + tid];
            #pragma unroll
            for (int rr = 0; rr < 16; ++rr) acc[rr] += sF[rr][f] * wf;
        }
        #pragma unroll
        for (int rr = 0; rr < 16; ++rr)
            h[(size_t)(row0 + rr) * DD + tid] = acc[rr];
        {
            const int t = tid & 63, r0 = tid >> 6;
            #pragma unroll
            for (int q = 0; q < 4; ++q) {
                int rr = r0 * 4 + q;
                float a = sCW[11][t];
                #pragma unroll
                for (int f = 0; f < 11; ++f) a += sF[rr][f] * sCW[f][t];
                preg[(size_t)(row0 + rr) * EH + t] = a;
            }
        }
        return;
    }
    if (blk > 232) {    // layer-cost: conv + split-k GEMM -> lpart
        const int lb = blk - 233;
        const int b = lb >> 5, kseg = (lb >> 2) & 7, c4 = lb & 3;
        const int d = tid & 63, ss = tid >> 6;
        __shared__ float sC[LL];
        __shared__ float sV[124];
        __shared__ float sP[4][64];
        if (tid < LL) sC[tid] = lc[b * LL + tid];
        __syncthreads();
        if (tid < 124) {
            int idx = kseg * 124 + tid;
            int c = idx / 31, t = idx - c * 31;
            float a = cb[c];
            #pragma unroll
            for (int k = 0; k < 4; ++k) a += sC[2 * t + k] * cw[c * 4 + k];
            sV[tid] = fmaxf(a, 0.f);
        }
        __syncthreads();
        float acc = 0.f;
        for (int k = ss; k < 124; k += 4)
            acc += sV[k] * lpw[(size_t)(kseg * 124 + k) * DD + c4 * 64 + d];
        sP[ss][d] = acc;
        __syncthreads();
        if (ss == 0)
            lpart[(b * 32 + kseg * 4 + c4) * 64 + d] = sP[0][d] + sP[1][d] + sP[2][d] + sP[3][d];
        return;
    }
    // weight transposes (f32 -> bf16, [K][D] -> [D][K])
    const float* src; unsigned short* dst; int K, kt, dt, srcw = 256;
    if (blk < 144)      { int l = blk / 48, t = blk % 48; kt = t >> 2; dt = t & 3;
                          src = uw1 + (size_t)l * 196608; dst = w1t + (size_t)l * 196608; K = 768; }
    else if (blk < 192) { int x = blk - 144, l = x / 16, t = x % 16; kt = t >> 2; dt = t & 3;
                          src = uw2 + (size_t)l * 65536; dst = w2t + (size_t)l * 65536; K = 256; }
    else if (blk < 204) { int x = blk - 192, l = x >> 2; kt = 0; dt = x & 3;
                          src = gw2 + (size_t)l * 16384; dst = g2t + (size_t)l * 16384; K = 64; }
    else if (blk < 216) { int x = blk - 204, l = x >> 2; kt = x & 3; dt = 0; srcw = 64;
                          src = gw1 + (size_t)l * 16576; dst = g1t + (size_t)l * 16384; K = 256; }
    else                { int x = blk - 216; kt = x >> 2; dt = x & 3;
                          src = kw; dst = kwt; K = 256; }
    __shared__ float sT[64][65];
    #pragma unroll
    for (int q = 0; q < 16; ++q) {
        int idx = q * 256 + tid, kk = idx >> 6, dd = idx & 63;
        sT[kk][dd] = src[(size_t)(kt * 64 + kk) * srcw + dt * 64 + dd];
    }
    __syncthreads();
    const int d = tid >> 2, kc = (tid & 3) * 16;
    unsigned short* drow = dst + (size_t)(dt * 64 + d) * K + kt * 64 + kc;
    #pragma unroll
    for (int i = 0; i < 16; ++i) drow[i] = (unsigned short)f2bf(sT[kc + i][d]);
}

// ---------------- per-layer fused: edge (4 rows) + update MLP + LN + tail ----------------
// Reads hin/pin, writes hout/pout (double-buffered across layers; no intra-kernel races:
// agg stays in LDS, blocks write only their own 4 rows of hout/pout).
__global__ __launch_bounds__(256) void k_layer(
    const float* __restrict__ hin, float* __restrict__ hout,
    const float* __restrict__ pin, float* __restrict__ pout,
    const float* __restrict__ ef, const void* __restrict__ adj,
    const int* __restrict__ mode, const float* __restrict__ gw1We,
    const unsigned short* __restrict__ g2t, const float* __restrict__ gb2,
    const unsigned short* __restrict__ w1t, const float* __restrict__ ub1,
    const unsigned short* __restrict__ w2t, const float* __restrict__ ub2,
    const float* __restrict__ lng, const float* __restrict__ lnb,
    const float* __restrict__ nf, float* __restrict__ out2,
    const unsigned short* __restrict__ g1tn, const float* __restrict__ gb1n,
    float* __restrict__ gpart)
{
    const int tid = threadIdx.x, bid = blockIdx.x;
    const int row0 = bid * 4, b = row0 >> 7;
    const int lane = tid & 63, w = tid >> 6;
    const int lcol = lane & 15, lrow = lane >> 4;
    const int md = mode[0];

    __shared__ __align__(16) char uA[32768];         // hid dbuf (edge) / sX32+sH16 (update)
    __shared__ float aggM[4][256], aggX[4][256];
    __shared__ float sRes[4][256];
    __shared__ float sOut[4][260];
    __shared__ float sWe[192];
    __shared__ float sE[4][384];
    __shared__ unsigned long long sMask[4][2];
    __shared__ float sWr[4];

    // ---- prologue ----
    if (tid < 192) sWe[tid] = gw1We[tid];
    for (int idx = tid; idx < 4 * 384; idx += 256) {
        int n = idx / 384, e = idx - n * 384;
        sE[n][e] = ef[(size_t)(row0 + n) * 384 + e];
    }
    #pragma unroll
    for (int n = 0; n < 4; ++n) {
        if (tid < 128) {
            size_t ai = (size_t)(row0 + n) * NN_ + tid;
            int mv;
            if (md == 1)      mv = ((const int*)adj)[ai] != 0;
            else if (md == 2) mv = ((const float*)adj)[ai] != 0.f;
            else              mv = ((const unsigned char*)adj)[ai] != 0;
            unsigned long long bal = __ballot(mv);
            if ((tid & 63) == 0) sMask[n][tid >> 6] = bal;
        }
    }
    if (tid < 4) {
        const float* p = nf + (size_t)(row0 + tid) * 11;
        sWr[tid] = p[0] * p[7];
    }
    bs8 bfr[4][2];
    float bg[4];
    #pragma unroll
    for (int nt = 0; nt < 4; ++nt) {
        int d = w * 64 + nt * 16 + lcol;
        bg[nt] = gb2[d];
        #pragma unroll
        for (int ks = 0; ks < 2; ++ks)
            bfr[nt][ks] = *(const bs8*)(g2t + (size_t)d * 64 + ks * 32 + lrow * 8);
    }

    const float* pB = pin + (size_t)b * NN_ * EH;
    const float* hB = hin + (size_t)b * NN_ * DD;
    unsigned int* const buf0 = (unsigned int*)uA;
    unsigned int* const buf1 = (unsigned int*)(uA + 16384);

    auto hidStage = [&](unsigned int* dst, int n) {
        #pragma unroll
        for (int q = 0; q < 16; ++q) {
            int idx = q * 256 + tid;
            int j = idx >> 5, p = idx & 31;
            float2 pv = *(const float2*)(pB + j * EH + 2 * p);
            float e0 = sE[n][j * 3], e1 = sE[n][j * 3 + 1], e2 = sE[n][j * 3 + 2];
            int t0 = 2 * p, t1 = t0 + 1;
            float v0 = fmaxf(pv.x + e0 * sWe[t0] + e1 * sWe[64 + t0] + e2 * sWe[128 + t0], 0.f);
            float v1 = fmaxf(pv.y + e0 * sWe[t1] + e1 * sWe[64 + t1] + e2 * sWe[128 + t1], 0.f);
            unsigned int pk = (unsigned int)(unsigned short)f2bf(v0) |
                              ((unsigned int)(unsigned short)f2bf(v1) << 16);
            dst[j * 32 + (p ^ ((j & 7) << 2))] = pk;
        }
    };

    __syncthreads();
    hidStage(buf0, 0);
    __syncthreads();
    int cur = 0;
    #pragma unroll
    for (int n = 0; n < 4; ++n) {
        if (n < 3) hidStage(cur ? buf0 : buf1, n + 1);
        {
            const unsigned int* sHid = cur ? buf1 : buf0;
            const unsigned long long m0 = sMask[n][0], m1 = sMask[n][1];
            const float cntf = (float)(__popcll(m0) + __popcll(m1));
            float vs[4] = {0.f, 0.f, 0.f, 0.f};
            float vm[4] = {-INFINITY, -INFINITY, -INFINITY, -INFINITY};
            #pragma unroll
            for (int pp = 0; pp < 2; ++pp) {
                f4 acc[4][4] = {};
                #pragma unroll
                for (int ks = 0; ks < 2; ++ks) {
                    bs8 afr[4];
                    #pragma unroll
                    for (int m = 0; m < 4; ++m) {
                        int j = pp * 64 + m * 16 + lcol;
                        int k0 = ks * 32 + lrow * 8;
                        afr[m] = *(const bs8*)(sHid + (j * 32 + ((k0 >> 1) ^ ((j & 7) << 2))));
                    }
                    #pragma unroll
                    for (int m = 0; m < 4; ++m)
                        #pragma unroll
                        for (int nt = 0; nt < 4; ++nt)
                            acc[m][nt] = __builtin_amdgcn_mfma_f32_16x16x32_bf16(
                                afr[m], bfr[nt][ks], acc[m][nt], 0, 0, 0);
                }
                const unsigned long long mw = pp ? m1 : m0;
                #pragma unroll
                for (int m = 0; m < 4; ++m) {
                    #pragma unroll
                    for (int nt = 0; nt < 4; ++nt) {
                        int dnt = w * 64 + nt * 16 + lcol;
                        #pragma unroll
                        for (int r = 0; r < 4; ++r) {
                            int bit = m * 16 + lrow * 4 + r;
                            float x = acc[m][nt][r] + bg[nt];
                            float g = __builtin_amdgcn_rcpf(1.0f + __expf(-x));
                            float msg = g * hB[(pp * 64 + bit) * DD + dnt];
                            int on = (int)((mw >> bit) & 1ULL);
                            vs[nt] += on ? msg : 0.f;
                            vm[nt] = fmaxf(vm[nt], on ? msg : -INFINITY);
                        }
                    }
                }
            }
            #pragma unroll
            for (int nt = 0; nt < 4; ++nt) {
                float s = vs[nt];
                s += __shfl_xor(s, 16); s += __shfl_xor(s, 32);
                vs[nt] = s;
                float m = vm[nt];
                m = fmaxf(m, __shfl_xor(m, 16)); m = fmaxf(m, __shfl_xor(m, 32));
                vm[nt] = m;
            }
            const int g = lrow;
            float ssel = (g == 0) ? vs[0] : (g == 1) ? vs[1] : (g == 2) ? vs[2] : vs[3];
            float msel = (g == 0) ? vm[0] : (g == 1) ? vm[1] : (g == 2) ? vm[2] : vm[3];
            const int d = w * 64 + lane;
            aggM[n][d] = ssel / fmaxf(cntf, 1.f);
            aggX[n][d] = (cntf > 0.f) ? msel : 0.f;
        }
        cur ^= 1;
        __syncthreads();
    }

    // ---- update MLP + residual + LN ----
    unsigned int* sX32 = (unsigned int*)uA;              // 24576 B
    unsigned short* sH16 = (unsigned short*)(uA + 24576); // 8192 B
    {
        const int j = w;
        const float* hR = hin + (size_t)(row0 + j) * DD;
        #pragma unroll
        for (int q = 0; q < 6; ++q) {
            int p = lane + q * 64;
            int k = 2 * p;
            float v0, v1;
            if (k < 256)      { float2 v = *(const float2*)(hR + k); v0 = v.x; v1 = v.y;
                                sRes[j][k] = v0; sRes[j][k + 1] = v1; }
            else if (k < 512) { v0 = aggM[j][k - 256]; v1 = aggM[j][k - 255]; }
            else              { v0 = aggX[j][k - 512]; v1 = aggX[j][k - 511]; }
            unsigned int pk = (unsigned int)(unsigned short)f2bf(v0) |
                              ((unsigned int)(unsigned short)f2bf(v1) << 16);
            sX32[j * 384 + (p ^ (j << 2))] = pk;
        }
    }
    __syncthreads();

    const char* sXb = (const char*)sX32;
    const unsigned short* w1r = w1t + (size_t)(w * 64 + lcol) * 768;
    f4 a0 = {0.f, 0.f, 0.f, 0.f}, a1 = a0, a2 = a0, a3 = a0;
    #pragma unroll 4
    for (int ks = 0; ks < 24; ++ks) {
        int k0 = ks * 32 + lrow * 8;
        bs8 av = *(const bs8*)(sXb + lcol * 1536 + ((((k0 >> 3) ^ (lcol & 7))) << 4));
        bs8 b0 = *(const bs8*)(w1r + k0);
        bs8 b1 = *(const bs8*)(w1r + 16 * 768 + k0);
        bs8 b2 = *(const bs8*)(w1r + 32 * 768 + k0);
        bs8 b3 = *(const bs8*)(w1r + 48 * 768 + k0);
        a0 = __builtin_amdgcn_mfma_f32_16x16x32_bf16(av, b0, a0, 0, 0, 0);
        a1 = __builtin_amdgcn_mfma_f32_16x16x32_bf16(av, b1, a1, 0, 0, 0);
        a2 = __builtin_amdgcn_mfma_f32_16x16x32_bf16(av, b2, a2, 0, 0, 0);
        a3 = __builtin_amdgcn_mfma_f32_16x16x32_bf16(av, b3, a3, 0, 0, 0);
    }
    if (lrow == 0) {
        #pragma unroll
        for (int nt = 0; nt < 4; ++nt) {
            int d = w * 64 + nt * 16 + lcol;
            float bb = ub1[d];
            f4 A = (nt == 0) ? a0 : (nt == 1) ? a1 : (nt == 2) ? a2 : a3;
            #pragma unroll
            for (int r = 0; r < 4; ++r) {
                float hv = fmaxf(A[r] + bb, 0.f);
                sH16[r * 256 + (d ^ (r << 3))] = (unsigned short)f2bf(hv);
            }
        }
    }
    __syncthreads();

    const unsigned short* w2r = w2t + (size_t)(w * 64 + lcol) * 256;
    f4 c0 = {0.f, 0.f, 0.f, 0.f}, c1 = c0, c2 = c0, c3 = c0;
    #pragma unroll
    for (int ks = 0; ks < 8; ++ks) {
        int k0 = ks * 32 + lrow * 8;
        bs8 av = *(const bs8*)((const char*)sH16 + lcol * 512 + ((((k0 >> 3) ^ (lcol & 7))) << 4));
        bs8 b0 = *(const bs8*)(w2r + k0);
        bs8 b1 = *(const bs8*)(w2r + 16 * 256 + k0);
        bs8 b2 = *(const bs8*)(w2r + 32 * 256 + k0);
        bs8 b3 = *(const bs8*)(w2r + 48 * 256 + k0);
        c0 = __builtin_amdgcn_mfma_f32_16x16x32_bf16(av, b0, c0, 0, 0, 0);
        c1 = __builtin_amdgcn_mfma_f32_16x16x32_bf16(av, b1, c1, 0, 0, 0);
        c2 = __builtin_amdgcn_mfma_f32_16x16x32_bf16(av, b2, c2, 0, 0, 0);
        c3 = __builtin_amdgcn_mfma_f32_16x16x32_bf16(av, b3, c3, 0, 0, 0);
    }
    if (lrow == 0) {
        #pragma unroll
        for (int nt = 0; nt < 4; ++nt) {
            int d = w * 64 + nt * 16 + lcol;
            float bb = ub2[d];
            f4 C = (nt == 0) ? c0 : (nt == 1) ? c1 : (nt == 2) ? c2 : c3;
            #pragma unroll
            for (int r = 0; r < 4; ++r)
                sOut[r][d] = C[r] + bb + sRes[r][d];
        }
    }
    __syncthreads();

    // LN: wave w handles row w
    float xv[4], s = 0.f;
    #pragma unroll
    for (int q = 0; q < 4; ++q) { xv[q] = sOut[w][lane + 64 * q]; s += xv[q]; }
    #pragma unroll
    for (int off = 1; off < 64; off <<= 1) s += __shfl_xor(s, off);
    const float mu = s * (1.f / DD);
    float s2 = 0.f;
    #pragma unroll
    for (int q = 0; q < 4; ++q) { float d = xv[q] - mu; s2 += d * d; }
    #pragma unroll
    for (int off = 1; off < 64; off <<= 1) s2 += __shfl_xor(s2, off);
    const float inv = rsqrtf(s2 * (1.f / DD) + 1e-5f);
    #pragma unroll
    for (int q = 0; q < 4; ++q) {
        int c = lane + 64 * q;
        float res = (xv[q] - mu) * inv * lng[c] + lnb[c];
        hout[(size_t)(row0 + w) * DD + c] = res;
        if (out2) out2[(size_t)(row0 + w) * DD + c] = res;
        sOut[w][c] = res;
    }
    __syncthreads();
    if (g1tn) {
        // fused next-layer pregate from post-LN rows (A rows 4-15 duplicate, discarded)
        const unsigned short* bR = g1tn + (size_t)(w * 16 + lcol) * 256;
        f4 p = {0.f, 0.f, 0.f, 0.f};
        #pragma unroll
        for (int ks = 0; ks < 8; ++ks) {
            int k0 = ks * 32 + lrow * 8;
            bs8 av = cvt8(&sOut[lcol & 3][k0]);
            bs8 bv = *(const bs8*)(bR + k0);
            p = __builtin_amdgcn_mfma_f32_16x16x32_bf16(av, bv, p, 0, 0, 0);
        }
        if (lrow == 0) {
            const float gb_ = gb1n[w * 16 + lcol];
            #pragma unroll
            for (int r = 0; r < 4; ++r)
                pout[(size_t)(row0 + r) * EH + w * 16 + lcol] = p[r] + gb_;
        }
    } else {
        // gembed partials (deterministic per-block)
        float g = sWr[0] * sOut[0][tid] + sWr[1] * sOut[1][tid] +
                  sWr[2] * sOut[2][tid] + sWr[3] * sOut[3][tid];
        gpart[(size_t)bid * DD + tid] = g;
    }
}

// ---------------- head GEMMs (unchanged from r10) ----------------
__global__ __launch_bounds__(256) void k_hmm(
    const float* __restrict__ gpart, const float* __restrict__ wsum,
    const float* __restrict__ gd,
    const float* __restrict__ qw, const float* __restrict__ sw1,
    const float* __restrict__ vw1,
    const float* __restrict__ lpb, const float* __restrict__ lpart,
    float* __restrict__ part)
{
    const int blk = blockIdx.x;
    const int m = blk >> 5, kseg = (blk >> 2) & 7, c4 = blk & 3;
    const int tid = threadIdx.x;
    const int d = tid & 63, ks = tid >> 6;
    const int K = (m == 1) ? 258 : 514;
    const int kc = (m == 1) ? 33 : 65;
    const int k0 = kseg * kc;
    const int klen = min(k0 + kc, K) - k0;
    __shared__ float sX[8 * 66];
    __shared__ float sP[4][8][64];
    for (int idx = tid; idx < 8 * kc; idx += 256) {
        int bb = idx / kc, kk = idx % kc, k = k0 + kk;
        float v = 0.f;
        if (k < K) {
            if (k < 256) {
                float s = 0.f;
                #pragma unroll 8
                for (int t = 0; t < 32; ++t)
                    s += gpart[(size_t)(bb * 32 + t) * DD + k];
                v = s / fmaxf(wsum[bb], 1e-8f);
            } else if (m == 1) {
                v = gd[bb * 2 + (k - 256)];
            } else if (k < 512) {
                int e = k - 256;
                v = lpb[e];
                #pragma unroll
                for (int s = 0; s < 8; ++s)
                    v += lpart[(bb * 32 + s * 4 + (e >> 6)) * 64 + (e & 63)];
            } else {
                v = gd[bb * 2 + (k - 512)];
            }
        }
        sX[bb * 66 + kk] = v;
    }
    __syncthreads();
    const float* W = (m == 0) ? qw : (m == 1) ? sw1 : vw1;
    const int dg = c4 * 64 + d;
    float acc[8] = {0.f, 0.f, 0.f, 0.f, 0.f, 0.f, 0.f, 0.f};
    for (int kk = ks; kk < klen; kk += 4) {
        float wv = W[(size_t)(k0 + kk) * DD + dg];
        #pragma unroll
        for (int bb = 0; bb < 8; ++bb) acc[bb] += sX[bb * 66 + kk] * wv;
    }
    #pragma unroll
    for (int bb = 0; bb < 8; ++bb) sP[ks][bb][d] = acc[bb];
    __syncthreads();
    for (int idx = tid; idx < 8 * 64; idx += 256) {
        int bb = idx >> 6, dd = idx & 63;
        float sum = sP[0][bb][dd] + sP[1][bb][dd] + sP[2][bb][dd] + sP[3][bb][dd];
        part[((m * 8 + kseg) * 8 + bb) * DD + c4 * 64 + dd] = sum;
    }
}

// ---------------- MFMA device scores + query reduce + stop/value (unchanged from r10) ----------------
__global__ __launch_bounds__(256) void k_scr(
    const float* __restrict__ h, const unsigned short* __restrict__ kwt,
    const float* __restrict__ kb, const float* __restrict__ hpart,
    const float* __restrict__ qb,
    const float* __restrict__ sb1, const float* __restrict__ vb1,
    const float* __restrict__ sw2, const float* __restrict__ sb2,
    const float* __restrict__ vw2, const float* __restrict__ vb2,
    float* __restrict__ out)
{
    const int tid = threadIdx.x, blk = blockIdx.x;
    const int row0 = blk * 16, b = blk >> 3, chunk = blk & 7;
    const int lane = tid & 63, w = tid >> 6;
    const int lcol = lane & 15, lrow = lane >> 4;
    __shared__ float sQ[256];
    __shared__ float sPart[4][16];
    __shared__ float sRed[256];
    {
        float qv = qb[tid];
        #pragma unroll
        for (int kseg = 0; kseg < 8; ++kseg)
            qv += hpart[(size_t)(kseg * 8 + b) * DD + tid];
        sQ[tid] = qv;
    }
    __syncthreads();
    const float* aR = h + (size_t)(row0 + lcol) * DD;
    f4 acc[4] = {};
    #pragma unroll
    for (int ks = 0; ks < 8; ++ks) {
        int k0 = ks * 32 + lrow * 8;
        bs8 av = cvt8(aR + k0);
        #pragma unroll
        for (int nt = 0; nt < 4; ++nt) {
            bs8 bv = *(const bs8*)(kwt + (size_t)(w * 64 + nt * 16 + lcol) * 256 + k0);
            acc[nt] = __builtin_amdgcn_mfma_f32_16x16x32_bf16(av, bv, acc[nt], 0, 0, 0);
        }
    }
    float part[4] = {0.f, 0.f, 0.f, 0.f};
    #pragma unroll
    for (int nt = 0; nt < 4; ++nt) {
        int col = w * 64 + nt * 16 + lcol;
        float q = sQ[col], kv = kb[col];
        #pragma unroll
        for (int r = 0; r < 4; ++r) part[r] += (acc[nt][r] + kv) * q;
    }
    #pragma unroll
    for (int r = 0; r < 4; ++r) {
        float s = part[r];
        s += __shfl_xor(s, 1); s += __shfl_xor(s, 2);
        s += __shfl_xor(s, 4); s += __shfl_xor(s, 8);
        part[r] = s;
    }
    if (lcol == 0) {
        #pragma unroll
        for (int r = 0; r < 4; ++r) sPart[w][lrow * 4 + r] = part[r];
    }
    __syncthreads();
    if (tid < 16) {
        float s = sPart[0][tid] + sPart[1][tid] + sPart[2][tid] + sPart[3][tid];
        out[b * 129 + (row0 & (NN_ - 1)) + tid] = s * 0.0625f;
    }
    if (chunk == 0) {
        float s = sb1[tid], v = vb1[tid];
        #pragma unroll
        for (int kseg = 0; kseg < 8; ++kseg) {
            s += hpart[(size_t)((8 + kseg) * 8 + b) * DD + tid];
            v += hpart[(size_t)((16 + kseg) * 8 + b) * DD + tid];
        }
        s = fmaxf(s, 0.f); v = fmaxf(v, 0.f);
        float stop = blockReduceSum(s * sw2[tid], sRed);
        float val  = blockReduceSum(v * vw2[tid], sRed);
        if (tid == 0) {
            out[b * 129 + 128] = stop + sb2[0];
            out[1032 + b] = val + vb2[0];
        }
    }
}

extern "C" void kernel_launch(void* const* d_in, const int* in_sizes, int n_in,
                              void* d_out, int out_size, void* d_ws, size_t ws_size,
                              hipStream_t stream) {
    (void)in_sizes; (void)n_in; (void)out_size; (void)ws_size;
    const float* nf  = (const float*)d_in[0];
    const float* ef  = (const float*)d_in[1];
    const void*  adj = d_in[2];
    const float* lc  = (const float*)d_in[3];
    const float* gd  = (const float*)d_in[4];
    const float* pnw = (const float*)d_in[5];
    const float* pnb = (const float*)d_in[6];
    const float* gw1 = (const float*)d_in[7];
    const float* gb1 = (const float*)d_in[8];
    const float* gw2 = (const float*)d_in[9];
    const float* gb2 = (const float*)d_in[10];
    const float* uw1 = (const float*)d_in[11];
    const float* ub1 = (const float*)d_in[12];
    const float* uw2 = (const float*)d_in[13];
    const float* ub2 = (const float*)d_in[14];
    const float* lng = (const float*)d_in[15];
    const float* lnb = (const float*)d_in[16];
    const float* cw  = (const float*)d_in[17];
    const float* cb  = (const float*)d_in[18];
    const float* lpw = (const float*)d_in[19];
    const float* lpb = (const float*)d_in[20];
    const float* qw  = (const float*)d_in[21];
    const float* qb  = (const float*)d_in[22];
    const float* kw  = (const float*)d_in[23];
    const float* kb  = (const float*)d_in[24];
    const float* sw1 = (const float*)d_in[25];
    const float* sb1 = (const float*)d_in[26];
    const float* sw2 = (const float*)d_in[27];
    const float* sb2 = (const float*)d_in[28];
    const float* vw1 = (const float*)d_in[29];
    const float* vb1 = (const float*)d_in[30];
    const float* vw2 = (const float*)d_in[31];
    const float* vb2 = (const float*)d_in[32];

    float* ws = (float*)d_ws;
    float* h0    = ws;                          // 262144
    float* h1    = ws + 262144;                 // 262144
    float* pregA = ws + 524288;                 // 65536
    float* pregB = ws + 589824;                 // 65536
    float* lpart = ws + 655360;                 // 16384
    float* hpart = ws + 671744;                 // 49152
    float* gpart = ws + 720896;                 // 65536
    float* wsum  = ws + 786432;                 // 8
    int*   mode  = (int*)(ws + 786440);         // 1 (pad to 786444)
    unsigned short* uw1t = (unsigned short*)(ws + 786444);    // 589824 shorts
    unsigned short* uw2t = (unsigned short*)(ws + 1081356);   // 196608 shorts
    unsigned short* g2t  = (unsigned short*)(ws + 1179660);   // 49152 shorts
    unsigned short* g1t  = (unsigned short*)(ws + 1204236);   // 49152 shorts
    unsigned short* kwt  = (unsigned short*)(ws + 1228812);   // 65536 shorts
    float* out   = (float*)d_out;

    k_prep<<<553, 256, 0, stream>>>(uw1, uw2, gw2, gw1, kw,
                                    (const unsigned char*)adj,
                                    lc, cw, cb, lpw, nf, pnw, pnb, gb1,
                                    uw1t, uw2t, g2t, g1t, kwt, mode, lpart, wsum,
                                    h0, pregA);
    float* hin = h0;  float* hout = h1;
    float* pin = pregA; float* pout = pregB;
    for (int i = 0; i < NG; ++i) {
        float* out2sel = (i == NG - 1) ? (out + 1040) : (float*)nullptr;
        const unsigned short* g1tn = (i < NG - 1) ? (g1t + (size_t)(i + 1) * 16384)
                                                  : (const unsigned short*)nullptr;
        const float* gb1n = (i < NG - 1) ? (gb1 + (i + 1) * EH) : (const float*)nullptr;
        k_layer<<<BB * NN_ / 4, 256, 0, stream>>>(hin, hout, pin, pout, ef, adj, mode,
                                                  gw1 + (size_t)i * 16576 + 16384,
                                                  g2t + (size_t)i * 16384, gb2 + i * DD,
                                                  uw1t + (size_t)i * 196608, ub1 + i * DD,
                                                  uw2t + (size_t)i * 65536, ub2 + i * DD,
                                                  lng + i * DD, lnb + i * DD, nf,
                                                  out2sel, g1tn, gb1n, gpart);
        float* t = hin; hin = hout; hout = t;
        t = pin; pin = pout; pout = t;
    }
    k_hmm<<<96, 256, 0, stream>>>(gpart, wsum, gd, qw, sw1, vw1, lpb, lpart, hpart);
    k_scr<<<BB * NN_ / 16, 256, 0, stream>>>(hin, kwt, kb, hpart, qb, sb1, vb1,
                                             sw2, sb2, vw2, vb2, out);
}

// Round 13
// 196.769 us; speedup vs baseline: 1.4495x; 1.4495x over previous
//
#include <hip/hip_runtime.h>
#include <hip/hip_bf16.h>
#include <math.h>

// Problem constants
#define BB 8
#define NN_ 128
#define DD 256
#define LL 64
#define EH 64
#define NG 3

typedef __attribute__((ext_vector_type(8))) short bs8;   // 8 bf16 (4 VGPR)
typedef __attribute__((ext_vector_type(4))) float f4;    // 4 f32
typedef __attribute__((ext_vector_type(4))) unsigned short us4;

__device__ __forceinline__ short f2bf(float f) {
    __hip_bfloat16 h = __float2bfloat16(f);
    return *reinterpret_cast<short*>(&h);
}

__device__ __forceinline__ float bf2f(unsigned short u) {
    unsigned int x = ((unsigned int)u) << 16;
    return __uint_as_float(x);
}

__device__ __forceinline__ bs8 cvt8(const float* __restrict__ p) {
    bs8 r;
    #pragma unroll
    for (int i = 0; i < 8; ++i) r[i] = f2bf(p[i]);
    return r;
}

__device__ __forceinline__ float blockReduceSum(float v, float* sRed) {
    int tid = threadIdx.x;
    __syncthreads();
    sRed[tid] = v;
    __syncthreads();
    for (int s = 128; s > 0; s >>= 1) {
        if (tid < s) sRed[tid] += sRed[tid + s];
        __syncthreads();
    }
    return sRed[0];
}

// ---------------- unified prep ----------------
// blocks 0..143 uw1^T, 144..191 uw2^T, 192..203 gw2^T, 204..215 gw1[:256]^T,
// 216..231 kw^T, 232 adj-probe+wsum, 233..488 layer-cost conv+GEMM,
// 489..552 nodeproj + composite layer-0 pregate (+ hT write)
__global__ __launch_bounds__(256) void k_prep(
    const float* __restrict__ uw1, const float* __restrict__ uw2,
    const float* __restrict__ gw2, const float* __restrict__ gw1,
    const float* __restrict__ kw, const unsigned char* __restrict__ adj,
    const float* __restrict__ lc, const float* __restrict__ cw,
    const float* __restrict__ cb, const float* __restrict__ lpw,
    const float* __restrict__ nf, const float* __restrict__ pnw,
    const float* __restrict__ pnb, const float* __restrict__ gb1,
    unsigned short* __restrict__ w1t, unsigned short* __restrict__ w2t,
    unsigned short* __restrict__ g2t, unsigned short* __restrict__ g1t,
    unsigned short* __restrict__ kwt, int* __restrict__ mode,
    float* __restrict__ lpart, float* __restrict__ wsum,
    float* __restrict__ h, float* __restrict__ preg,
    unsigned short* __restrict__ hT)
{
    const int blk = blockIdx.x, tid = threadIdx.x;
    if (blk == 232) {   // adj dtype probe + wsum
        __shared__ int sOff, sBig;
        __shared__ float sRedD[256];
        if (tid == 0) { sOff = 0; sBig = 0; }
        __syncthreads();
        int off = 0, big = 0;
        #pragma unroll
        for (int k = 0; k < 4; ++k) {
            unsigned char v = adj[tid * 4 + k];
            if (v > 1) big = 1;
            if (k != 0 && v != 0) off = 1;
        }
        if (off) atomicOr(&sOff, 1);
        if (big) atomicOr(&sBig, 1);
        __syncthreads();
        if (tid == 0) mode[0] = sBig ? 2 : (sOff ? 0 : 1);
        for (int bb = 0; bb < 8; ++bb) {
            float v = 0.f;
            if (tid < 128) {
                const float* p = nf + (size_t)(bb * 128 + tid) * 11;
                v = p[0] * p[7];
            }
            float s = blockReduceSum(v, sRedD);
            if (tid == 0) wsum[bb] = s;
        }
        return;
    }
    if (blk >= 489) {   // nodeproj + composite layer-0 pregate (16 rows)
        const int row0 = (blk - 489) * 16;
        const int b = row0 >> 7, n0 = row0 & 127;
        __shared__ float sF[16][12];
        __shared__ float sCW[12][64];
        if (tid < 176) sF[tid / 11][tid % 11] = nf[(size_t)(row0 + tid / 11) * 11 + tid % 11];
        {
            const int t = tid & 63, f0 = tid >> 6;
            const float* r0p = pnw + (size_t)f0 * DD;
            const float* r1p = pnw + (size_t)(f0 + 4) * DD;
            const float* r2p = (f0 + 8 < 11) ? (pnw + (size_t)(f0 + 8) * DD) : pnb;
            float a0 = 0.f, a1 = 0.f, a2 = 0.f;
            for (int k = 0; k < 256; ++k) {
                float g = gw1[k * EH + t];
                a0 += r0p[k] * g; a1 += r1p[k] * g; a2 += r2p[k] * g;
            }
            if (f0 + 8 == 11) a2 += gb1[t];
            sCW[f0][t] = a0; sCW[f0 + 4][t] = a1; sCW[f0 + 8][t] = a2;
        }
        __syncthreads();
        float acc[16];
        {
            float bb = pnb[tid];
            #pragma unroll
            for (int rr = 0; rr < 16; ++rr) acc[rr] = bb;
        }
        #pragma unroll
        for (int f = 0; f < 11; ++f) {
            float wf = pnw[f * DD + tid];
            #pragma unroll
            for (int rr = 0; rr < 16; ++rr) acc[rr] += sF[rr][f] * wf;
        }
        unsigned short* hTb = hT + ((size_t)b * 256 + tid) * 128 + n0;
        #pragma unroll
        for (int rr = 0; rr < 16; ++rr) {
            h[(size_t)(row0 + rr) * DD + tid] = acc[rr];
            hTb[rr] = (unsigned short)f2bf(acc[rr]);
        }
        {
            const int t = tid & 63, r0 = tid >> 6;
            #pragma unroll
            for (int q = 0; q < 4; ++q) {
                int rr = r0 * 4 + q;
                float a = sCW[11][t];
                #pragma unroll
                for (int f = 0; f < 11; ++f) a += sF[rr][f] * sCW[f][t];
                preg[(size_t)(row0 + rr) * EH + t] = a;
            }
        }
        return;
    }
    if (blk > 232) {    // layer-cost: conv + split-k GEMM -> lpart
        const int lb = blk - 233;
        const int b = lb >> 5, kseg = (lb >> 2) & 7, c4 = lb & 3;
        const int d = tid & 63, ss = tid >> 6;
        __shared__ float sC[LL];
        __shared__ float sV[124];
        __shared__ float sP[4][64];
        if (tid < LL) sC[tid] = lc[b * LL + tid];
        __syncthreads();
        if (tid < 124) {
            int idx = kseg * 124 + tid;
            int c = idx / 31, t = idx - c * 31;
            float a = cb[c];
            #pragma unroll
            for (int k = 0; k < 4; ++k) a += sC[2 * t + k] * cw[c * 4 + k];
            sV[tid] = fmaxf(a, 0.f);
        }
        __syncthreads();
        float acc = 0.f;
        for (int k = ss; k < 124; k += 4)
            acc += sV[k] * lpw[(size_t)(kseg * 124 + k) * DD + c4 * 64 + d];
        sP[ss][d] = acc;
        __syncthreads();
        if (ss == 0)
            lpart[(b * 32 + kseg * 4 + c4) * 64 + d] = sP[0][d] + sP[1][d] + sP[2][d] + sP[3][d];
        return;
    }
    // weight transposes (f32 -> bf16, [K][D] -> [D][K])
    const float* src; unsigned short* dst; int K, kt, dt, srcw = 256;
    if (blk < 144)      { int l = blk / 48, t = blk % 48; kt = t >> 2; dt = t & 3;
                          src = uw1 + (size_t)l * 196608; dst = w1t + (size_t)l * 196608; K = 768; }
    else if (blk < 192) { int x = blk - 144, l = x / 16, t = x % 16; kt = t >> 2; dt = t & 3;
                          src = uw2 + (size_t)l * 65536; dst = w2t + (size_t)l * 65536; K = 256; }
    else if (blk < 204) { int x = blk - 192, l = x >> 2; kt = 0; dt = x & 3;
                          src = gw2 + (size_t)l * 16384; dst = g2t + (size_t)l * 16384; K = 64; }
    else if (blk < 216) { int x = blk - 204, l = x >> 2; kt = x & 3; dt = 0; srcw = 64;
                          src = gw1 + (size_t)l * 16576; dst = g1t + (size_t)l * 16384; K = 256; }
    else                { int x = blk - 216; kt = x >> 2; dt = x & 3;
                          src = kw; dst = kwt; K = 256; }
    __shared__ float sT[64][65];
    #pragma unroll
    for (int q = 0; q < 16; ++q) {
        int idx = q * 256 + tid, kk = idx >> 6, dd = idx & 63;
        sT[kk][dd] = src[(size_t)(kt * 64 + kk) * srcw + dt * 64 + dd];
    }
    __syncthreads();
    const int d = tid >> 2, kc = (tid & 3) * 16;
    unsigned short* drow = dst + (size_t)(dt * 64 + d) * K + kt * 64 + kc;
    #pragma unroll
    for (int i = 0; i < 16; ++i) drow[i] = (unsigned short)f2bf(sT[kc + i][d]);
}

// ---------------- fused edge-gate (MFMA) + masked aggregation ----------------
// h_j values read from transposed bf16 hT[b][d][n]: 8B vector loads
__global__ __launch_bounds__(256) void k_edge(
    const unsigned short* __restrict__ hT, const float* __restrict__ preg,
    const float* __restrict__ edge, const void* __restrict__ adj,
    const int* __restrict__ mode,
    const float* __restrict__ gw1,   // layer base (259,64)
    const unsigned short* __restrict__ g2t,
    const float* __restrict__ gb2,
    float* __restrict__ agg_mean, float* __restrict__ agg_max)
{
    const int tid = threadIdx.x;
    const int bi = blockIdx.x;
    const int b = bi >> 7;
    const int lane = tid & 63, w = tid >> 6;
    const int lrow = lane >> 4, lcol = lane & 15;
    const int md = mode[0];

    __shared__ __align__(16) unsigned int sHid[4096];
    __shared__ float sWe[192];
    __shared__ float sE[384];
    __shared__ unsigned long long sMask[2];

    if (tid < 192) sWe[tid] = gw1[16384 + tid];
    const float* eB = edge + (size_t)bi * 384;
    for (int idx = tid; idx < 384; idx += 256) sE[idx] = eB[idx];
    if (tid < 128) {
        int mv;
        if (md == 1)      mv = ((const int*)adj)[(size_t)bi * NN_ + tid] != 0;
        else if (md == 2) mv = ((const float*)adj)[(size_t)bi * NN_ + tid] != 0.f;
        else              mv = ((const unsigned char*)adj)[(size_t)bi * NN_ + tid] != 0;
        unsigned long long bal = __ballot(mv);
        if ((tid & 63) == 0) sMask[tid >> 6] = bal;
    }
    __syncthreads();

    const float* pB = preg + (size_t)b * NN_ * EH;
    #pragma unroll
    for (int q = 0; q < 16; ++q) {
        int idx = q * 256 + tid;
        int j = idx >> 5, p = idx & 31;
        float2 pv = *(const float2*)(pB + j * EH + 2 * p);
        float e0 = sE[j * 3], e1 = sE[j * 3 + 1], e2 = sE[j * 3 + 2];
        int t0 = 2 * p, t1 = t0 + 1;
        float v0 = fmaxf(pv.x + e0 * sWe[t0] + e1 * sWe[64 + t0] + e2 * sWe[128 + t0], 0.f);
        float v1 = fmaxf(pv.y + e0 * sWe[t1] + e1 * sWe[64 + t1] + e2 * sWe[128 + t1], 0.f);
        unsigned int pk = (unsigned int)(unsigned short)f2bf(v0) |
                          ((unsigned int)(unsigned short)f2bf(v1) << 16);
        sHid[j * 32 + (p ^ ((j & 7) << 2))] = pk;
    }
    __syncthreads();

    const unsigned long long m0 = sMask[0], m1 = sMask[1];
    const float cntf = (float)(__popcll(m0) + __popcll(m1));

    bs8 bfr[4][2];
    float bg[4];
    #pragma unroll
    for (int nt = 0; nt < 4; ++nt) {
        int d = w * 64 + nt * 16 + lcol;
        bg[nt] = gb2[d];
        #pragma unroll
        for (int ks = 0; ks < 2; ++ks) {
            int k0 = ks * 32 + lrow * 8;
            bfr[nt][ks] = *(const bs8*)(g2t + (size_t)d * 64 + k0);
        }
    }

    const unsigned short* hTb = hT + (size_t)b * 256 * 128;
    float vs[4] = {0.f, 0.f, 0.f, 0.f};
    float vm[4] = {-INFINITY, -INFINITY, -INFINITY, -INFINITY};

    #pragma unroll
    for (int pp = 0; pp < 2; ++pp) {
        f4 acc[4][4] = {};
        #pragma unroll
        for (int ks = 0; ks < 2; ++ks) {
            bs8 afr[4];
            #pragma unroll
            for (int m = 0; m < 4; ++m) {
                int j = pp * 64 + m * 16 + lcol;
                int k0 = ks * 32 + lrow * 8;
                afr[m] = *(const bs8*)(sHid + (j * 32 + ((k0 >> 1) ^ ((j & 7) << 2))));
            }
            #pragma unroll
            for (int m = 0; m < 4; ++m)
                #pragma unroll
                for (int nt = 0; nt < 4; ++nt)
                    acc[m][nt] = __builtin_amdgcn_mfma_f32_16x16x32_bf16(
                        afr[m], bfr[nt][ks], acc[m][nt], 0, 0, 0);
        }
        const unsigned long long mw = pp ? m1 : m0;
        #pragma unroll
        for (int m = 0; m < 4; ++m) {
            #pragma unroll
            for (int nt = 0; nt < 4; ++nt) {
                int dnt = w * 64 + nt * 16 + lcol;
                // rows (r=0..3) contiguous in hT: one 8B load
                us4 hv = *(const us4*)(hTb + (size_t)dnt * 128 + pp * 64 + m * 16 + lrow * 4);
                #pragma unroll
                for (int r = 0; r < 4; ++r) {
                    int bit = m * 16 + lrow * 4 + r;
                    float x = acc[m][nt][r] + bg[nt];
                    float g = __builtin_amdgcn_rcpf(1.0f + __expf(-x));
                    float msg = g * bf2f(hv[r]);
                    int on = (int)((mw >> bit) & 1ULL);
                    vs[nt] += on ? msg : 0.f;
                    vm[nt] = fmaxf(vm[nt], on ? msg : -INFINITY);
                }
            }
        }
    }

    #pragma unroll
    for (int nt = 0; nt < 4; ++nt) {
        float s = vs[nt];
        s += __shfl_xor(s, 16); s += __shfl_xor(s, 32);
        vs[nt] = s;
        float m = vm[nt];
        m = fmaxf(m, __shfl_xor(m, 16)); m = fmaxf(m, __shfl_xor(m, 32));
        vm[nt] = m;
    }
    const int g = lrow;
    float ssel = (g == 0) ? vs[0] : (g == 1) ? vs[1] : (g == 2) ? vs[2] : vs[3];
    float msel = (g == 0) ? vm[0] : (g == 1) ? vm[1] : (g == 2) ? vm[2] : vm[3];
    const int d = w * 64 + lane;
    agg_mean[(size_t)bi * DD + d] = ssel / fmaxf(cntf, 1.f);
    agg_max[(size_t)bi * DD + d] = (cntf > 0.f) ? msel : 0.f;
}

// ---------------- MFMA update MLP + residual + LN + fused next pregate / gembed partials ----------------
__global__ __launch_bounds__(256) void k_updp(
    const float* __restrict__ h, const float* __restrict__ amean,
    const float* __restrict__ amax, const float* __restrict__ nf,
    const unsigned short* __restrict__ w1t,
    const float* __restrict__ ub1,
    const unsigned short* __restrict__ w2t,
    const float* __restrict__ ub2,
    const float* __restrict__ lng, const float* __restrict__ lnb,
    float* __restrict__ hout, float* __restrict__ out2,
    const unsigned short* __restrict__ g1tn, const float* __restrict__ gb1n,
    float* __restrict__ preg, float* __restrict__ gpart,
    unsigned short* __restrict__ hT)
{
    const int tid = threadIdx.x;
    const int row0 = blockIdx.x * 4;
    const int lane = tid & 63, w = tid >> 6;
    const int lcol = lane & 15, lrow = lane >> 4;
    const int b = row0 >> 7, n0 = row0 & 127;

    __shared__ __align__(16) unsigned int sX32[16 * 384];
    __shared__ __align__(16) unsigned short sH16[16 * 256];
    __shared__ float sRes[4][256];
    __shared__ float sOut[4][260];   // +4 pad
    __shared__ float sWr[4];

    if (tid < 4) {
        const float* p = nf + (size_t)(row0 + tid) * 11;
        sWr[tid] = p[0] * p[7];
    }
    {
        const int j = w;
        const float* hR = h + (size_t)(row0 + j) * DD;
        const float* mR = amean + (size_t)(row0 + j) * DD;
        const float* xR = amax + (size_t)(row0 + j) * DD;
        #pragma unroll
        for (int q = 0; q < 6; ++q) {
            int p = lane + q * 64;
            int k = 2 * p;
            float2 v;
            if (k < 256)      { v = *(const float2*)(hR + k); sRes[j][k] = v.x; sRes[j][k + 1] = v.y; }
            else if (k < 512)   v = *(const float2*)(mR + (k - 256));
            else                v = *(const float2*)(xR + (k - 512));
            unsigned int pk = (unsigned int)(unsigned short)f2bf(v.x) |
                              ((unsigned int)(unsigned short)f2bf(v.y) << 16);
            sX32[j * 384 + (p ^ (j << 2))] = pk;
        }
    }
    __syncthreads();

    const char* sXb = (const char*)sX32;
    const unsigned short* w1r = w1t + (size_t)(w * 64 + lcol) * 768;
    f4 a0 = {0.f, 0.f, 0.f, 0.f}, a1 = a0, a2 = a0, a3 = a0;
    #pragma unroll 4
    for (int ks = 0; ks < 24; ++ks) {
        int k0 = ks * 32 + lrow * 8;
        bs8 av = *(const bs8*)(sXb + lcol * 1536 + ((((k0 >> 3) ^ (lcol & 7))) << 4));
        bs8 b0 = *(const bs8*)(w1r + k0);
        bs8 b1 = *(const bs8*)(w1r + 16 * 768 + k0);
        bs8 b2 = *(const bs8*)(w1r + 32 * 768 + k0);
        bs8 b3 = *(const bs8*)(w1r + 48 * 768 + k0);
        a0 = __builtin_amdgcn_mfma_f32_16x16x32_bf16(av, b0, a0, 0, 0, 0);
        a1 = __builtin_amdgcn_mfma_f32_16x16x32_bf16(av, b1, a1, 0, 0, 0);
        a2 = __builtin_amdgcn_mfma_f32_16x16x32_bf16(av, b2, a2, 0, 0, 0);
        a3 = __builtin_amdgcn_mfma_f32_16x16x32_bf16(av, b3, a3, 0, 0, 0);
    }
    if (lrow == 0) {
        #pragma unroll
        for (int nt = 0; nt < 4; ++nt) {
            int d = w * 64 + nt * 16 + lcol;
            float bb = ub1[d];
            f4 A = (nt == 0) ? a0 : (nt == 1) ? a1 : (nt == 2) ? a2 : a3;
            #pragma unroll
            for (int r = 0; r < 4; ++r) {
                float hv = fmaxf(A[r] + bb, 0.f);
                sH16[r * 256 + (d ^ (r << 3))] = (unsigned short)f2bf(hv);
            }
        }
    }
    __syncthreads();

    const unsigned short* w2r = w2t + (size_t)(w * 64 + lcol) * 256;
    f4 c0 = {0.f, 0.f, 0.f, 0.f}, c1 = c0, c2 = c0, c3 = c0;
    #pragma unroll
    for (int ks = 0; ks < 8; ++ks) {
        int k0 = ks * 32 + lrow * 8;
        bs8 av = *(const bs8*)((const char*)sH16 + lcol * 512 + ((((k0 >> 3) ^ (lcol & 7))) << 4));
        bs8 b0 = *(const bs8*)(w2r + k0);
        bs8 b1 = *(const bs8*)(w2r + 16 * 256 + k0);
        bs8 b2 = *(const bs8*)(w2r + 32 * 256 + k0);
        bs8 b3 = *(const bs8*)(w2r + 48 * 256 + k0);
        c0 = __builtin_amdgcn_mfma_f32_16x16x32_bf16(av, b0, c0, 0, 0, 0);
        c1 = __builtin_amdgcn_mfma_f32_16x16x32_bf16(av, b1, c1, 0, 0, 0);
        c2 = __builtin_amdgcn_mfma_f32_16x16x32_bf16(av, b2, c2, 0, 0, 0);
        c3 = __builtin_amdgcn_mfma_f32_16x16x32_bf16(av, b3, c3, 0, 0, 0);
    }
    if (lrow == 0) {
        #pragma unroll
        for (int nt = 0; nt < 4; ++nt) {
            int d = w * 64 + nt * 16 + lcol;
            float bb = ub2[d];
            f4 C = (nt == 0) ? c0 : (nt == 1) ? c1 : (nt == 2) ? c2 : c3;
            #pragma unroll
            for (int r = 0; r < 4; ++r)
                sOut[r][d] = C[r] + bb + sRes[r][d];
        }
    }
    __syncthreads();

    // LN: wave w handles row w
    float xv[4], s = 0.f;
    #pragma unroll
    for (int q = 0; q < 4; ++q) { xv[q] = sOut[w][lane + 64 * q]; s += xv[q]; }
    #pragma unroll
    for (int off = 1; off < 64; off <<= 1) s += __shfl_xor(s, off);
    const float mu = s * (1.f / DD);
    float s2 = 0.f;
    #pragma unroll
    for (int q = 0; q < 4; ++q) { float d = xv[q] - mu; s2 += d * d; }
    #pragma unroll
    for (int off = 1; off < 64; off <<= 1) s2 += __shfl_xor(s2, off);
    const float inv = rsqrtf(s2 * (1.f / DD) + 1e-5f);
    #pragma unroll
    for (int q = 0; q < 4; ++q) {
        int c = lane + 64 * q;
        float res = (xv[q] - mu) * inv * lng[c] + lnb[c];
        hout[(size_t)(row0 + w) * DD + c] = res;
        if (out2) out2[(size_t)(row0 + w) * DD + c] = res;
        hT[((size_t)b * 256 + c) * 128 + n0 + w] = (unsigned short)f2bf(res);
        sOut[w][c] = res;
    }
    __syncthreads();
    if (g1tn) {
        // fused next-layer pregate from post-LN rows (A rows 4-15 duplicate, discarded)
        const unsigned short* bR = g1tn + (size_t)(w * 16 + lcol) * 256;
        f4 p = {0.f, 0.f, 0.f, 0.f};
        #pragma unroll
        for (int ks = 0; ks < 8; ++ks) {
            int k0 = ks * 32 + lrow * 8;
            bs8 av = cvt8(&sOut[lcol & 3][k0]);
            bs8 bv = *(const bs8*)(bR + k0);
            p = __builtin_amdgcn_mfma_f32_16x16x32_bf16(av, bv, p, 0, 0, 0);
        }
        if (lrow == 0) {
            const float gb_ = gb1n[w * 16 + lcol];
            #pragma unroll
            for (int r = 0; r < 4; ++r)
                preg[(size_t)(row0 + r) * EH + w * 16 + lcol] = p[r] + gb_;
        }
    } else {
        // gembed partials (deterministic per-block)
        float g = sWr[0] * sOut[0][tid] + sWr[1] * sOut[1][tid] +
                  sWr[2] * sOut[2][tid] + sWr[3] * sOut[3][tid];
        gpart[(size_t)blockIdx.x * DD + tid] = g;
    }
}

// ---------------- head GEMMs ----------------
__global__ __launch_bounds__(256) void k_hmm(
    const float* __restrict__ gpart, const float* __restrict__ wsum,
    const float* __restrict__ gd,
    const float* __restrict__ qw, const float* __restrict__ sw1,
    const float* __restrict__ vw1,
    const float* __restrict__ lpb, const float* __restrict__ lpart,
    float* __restrict__ part)
{
    const int blk = blockIdx.x;
    const int m = blk >> 5, kseg = (blk >> 2) & 7, c4 = blk & 3;
    const int tid = threadIdx.x;
    const int d = tid & 63, ks = tid >> 6;
    const int K = (m == 1) ? 258 : 514;
    const int kc = (m == 1) ? 33 : 65;
    const int k0 = kseg * kc;
    const int klen = min(k0 + kc, K) - k0;
    __shared__ float sX[8 * 66];
    __shared__ float sP[4][8][64];
    for (int idx = tid; idx < 8 * kc; idx += 256) {
        int bb = idx / kc, kk = idx % kc, k = k0 + kk;
        float v = 0.f;
        if (k < K) {
            if (k < 256) {
                float s = 0.f;
                #pragma unroll 8
                for (int t = 0; t < 32; ++t)
                    s += gpart[(size_t)(bb * 32 + t) * DD + k];
                v = s / fmaxf(wsum[bb], 1e-8f);
            } else if (m == 1) {
                v = gd[bb * 2 + (k - 256)];
            } else if (k < 512) {
                int e = k - 256;
                v = lpb[e];
                #pragma unroll
                for (int s = 0; s < 8; ++s)
                    v += lpart[(bb * 32 + s * 4 + (e >> 6)) * 64 + (e & 63)];
            } else {
                v = gd[bb * 2 + (k - 512)];
            }
        }
        sX[bb * 66 + kk] = v;
    }
    __syncthreads();
    const float* W = (m == 0) ? qw : (m == 1) ? sw1 : vw1;
    const int dg = c4 * 64 + d;
    float acc[8] = {0.f, 0.f, 0.f, 0.f, 0.f, 0.f, 0.f, 0.f};
    for (int kk = ks; kk < klen; kk += 4) {
        float wv = W[(size_t)(k0 + kk) * DD + dg];
        #pragma unroll
        for (int bb = 0; bb < 8; ++bb) acc[bb] += sX[bb * 66 + kk] * wv;
    }
    #pragma unroll
    for (int bb = 0; bb < 8; ++bb) sP[ks][bb][d] = acc[bb];
    __syncthreads();
    for (int idx = tid; idx < 8 * 64; idx += 256) {
        int bb = idx >> 6, dd = idx & 63;
        float sum = sP[0][bb][dd] + sP[1][bb][dd] + sP[2][bb][dd] + sP[3][bb][dd];
        part[((m * 8 + kseg) * 8 + bb) * DD + c4 * 64 + dd] = sum;
    }
}

// ---------------- MFMA device scores + query reduce + stop/value ----------------
__global__ __launch_bounds__(256) void k_scr(
    const float* __restrict__ h, const unsigned short* __restrict__ kwt,
    const float* __restrict__ kb, const float* __restrict__ hpart,
    const float* __restrict__ qb,
    const float* __restrict__ sb1, const float* __restrict__ vb1,
    const float* __restrict__ sw2, const float* __restrict__ sb2,
    const float* __restrict__ vw2, const float* __restrict__ vb2,
    float* __restrict__ out)
{
    const int tid = threadIdx.x, blk = blockIdx.x;
    const int row0 = blk * 16, b = blk >> 3, chunk = blk & 7;
    const int lane = tid & 63, w = tid >> 6;
    const int lcol = lane & 15, lrow = lane >> 4;
    __shared__ float sQ[256];
    __shared__ float sPart[4][16];
    __shared__ float sRed[256];
    {
        float qv = qb[tid];
        #pragma unroll
        for (int kseg = 0; kseg < 8; ++kseg)
            qv += hpart[(size_t)(kseg * 8 + b) * DD + tid];
        sQ[tid] = qv;
    }
    __syncthreads();
    const float* aR = h + (size_t)(row0 + lcol) * DD;
    f4 acc[4] = {};
    #pragma unroll
    for (int ks = 0; ks < 8; ++ks) {
        int k0 = ks * 32 + lrow * 8;
        bs8 av = cvt8(aR + k0);
        #pragma unroll
        for (int nt = 0; nt < 4; ++nt) {
            bs8 bv = *(const bs8*)(kwt + (size_t)(w * 64 + nt * 16 + lcol) * 256 + k0);
            acc[nt] = __builtin_amdgcn_mfma_f32_16x16x32_bf16(av, bv, acc[nt], 0, 0, 0);
        }
    }
    float part[4] = {0.f, 0.f, 0.f, 0.f};
    #pragma unroll
    for (int nt = 0; nt < 4; ++nt) {
        int col = w * 64 + nt * 16 + lcol;
        float q = sQ[col], kv = kb[col];
        #pragma unroll
        for (int r = 0; r < 4; ++r) part[r] += (acc[nt][r] + kv) * q;
    }
    #pragma unroll
    for (int r = 0; r < 4; ++r) {
        float s = part[r];
        s += __shfl_xor(s, 1); s += __shfl_xor(s, 2);
        s += __shfl_xor(s, 4); s += __shfl_xor(s, 8);
        part[r] = s;
    }
    if (lcol == 0) {
        #pragma unroll
        for (int r = 0; r < 4; ++r) sPart[w][lrow * 4 + r] = part[r];
    }
    __syncthreads();
    if (tid < 16) {
        float s = sPart[0][tid] + sPart[1][tid] + sPart[2][tid] + sPart[3][tid];
        out[b * 129 + (row0 & (NN_ - 1)) + tid] = s * 0.0625f;
    }
    if (chunk == 0) {
        float s = sb1[tid], v = vb1[tid];
        #pragma unroll
        for (int kseg = 0; kseg < 8; ++kseg) {
            s += hpart[(size_t)((8 + kseg) * 8 + b) * DD + tid];
            v += hpart[(size_t)((16 + kseg) * 8 + b) * DD + tid];
        }
        s = fmaxf(s, 0.f); v = fmaxf(v, 0.f);
        float stop = blockReduceSum(s * sw2[tid], sRed);
        float val  = blockReduceSum(v * vw2[tid], sRed);
        if (tid == 0) {
            out[b * 129 + 128] = stop + sb2[0];
            out[1032 + b] = val + vb2[0];
        }
    }
}

extern "C" void kernel_launch(void* const* d_in, const int* in_sizes, int n_in,
                              void* d_out, int out_size, void* d_ws, size_t ws_size,
                              hipStream_t stream) {
    (void)in_sizes; (void)n_in; (void)out_size; (void)ws_size;
    const float* nf  = (const float*)d_in[0];
    const float* ef  = (const float*)d_in[1];
    const void*  adj = d_in[2];
    const float* lc  = (const float*)d_in[3];
    const float* gd  = (const float*)d_in[4];
    const float* pnw = (const float*)d_in[5];
    const float* pnb = (const float*)d_in[6];
    const float* gw1 = (const float*)d_in[7];
    const float* gb1 = (const float*)d_in[8];
    const float* gw2 = (const float*)d_in[9];
    const float* gb2 = (const float*)d_in[10];
    const float* uw1 = (const float*)d_in[11];
    const float* ub1 = (const float*)d_in[12];
    const float* uw2 = (const float*)d_in[13];
    const float* ub2 = (const float*)d_in[14];
    const float* lng = (const float*)d_in[15];
    const float* lnb = (const float*)d_in[16];
    const float* cw  = (const float*)d_in[17];
    const float* cb  = (const float*)d_in[18];
    const float* lpw = (const float*)d_in[19];
    const float* lpb = (const float*)d_in[20];
    const float* qw  = (const float*)d_in[21];
    const float* qb  = (const float*)d_in[22];
    const float* kw  = (const float*)d_in[23];
    const float* kb  = (const float*)d_in[24];
    const float* sw1 = (const float*)d_in[25];
    const float* sb1 = (const float*)d_in[26];
    const float* sw2 = (const float*)d_in[27];
    const float* sb2 = (const float*)d_in[28];
    const float* vw1 = (const float*)d_in[29];
    const float* vb1 = (const float*)d_in[30];
    const float* vw2 = (const float*)d_in[31];
    const float* vb2 = (const float*)d_in[32];

    float* ws = (float*)d_ws;
    float* h0    = ws;                          // 262144
    float* h1    = ws + 262144;                 // 262144
    float* pregA = ws + 524288;                 // 65536
    float* pregB = ws + 589824;                 // 65536
    float* amean = ws + 655360;                 // 262144
    float* amax  = ws + 917504;                 // 262144
    float* lpart = ws + 1179648;                // 16384
    float* hpart = ws + 1196032;                // 49152
    float* gpart = ws + 1245184;                // 65536
    float* wsum  = ws + 1310720;                // 8
    int*   mode  = (int*)(ws + 1310728);        // 1 (pad to 1310732)
    unsigned short* uw1t = (unsigned short*)(ws + 1310732);   // 589824 shorts
    unsigned short* uw2t = (unsigned short*)(ws + 1605644);   // 196608 shorts
    unsigned short* g2t  = (unsigned short*)(ws + 1703948);   // 49152 shorts
    unsigned short* g1t  = (unsigned short*)(ws + 1728524);   // 49152 shorts
    unsigned short* kwt  = (unsigned short*)(ws + 1753100);   // 65536 shorts
    unsigned short* hT   = (unsigned short*)(ws + 1785868);   // 262144 shorts (bf16 h^T)
    float* out   = (float*)d_out;

    k_prep<<<553, 256, 0, stream>>>(uw1, uw2, gw2, gw1, kw,
                                    (const unsigned char*)adj,
                                    lc, cw, cb, lpw, nf, pnw, pnb, gb1,
                                    uw1t, uw2t, g2t, g1t, kwt, mode, lpart, wsum,
                                    h0, pregA, hT);
    float* hin = h0;  float* hout = h1;
    float* pin = pregA; float* pout = pregB;
    for (int i = 0; i < NG; ++i) {
        float* out2sel = (i == NG - 1) ? (out + 1040) : (float*)nullptr;
        const unsigned short* g1tn = (i < NG - 1) ? (g1t + (size_t)(i + 1) * 16384)
                                                  : (const unsigned short*)nullptr;
        const float* gb1n = (i < NG - 1) ? (gb1 + (i + 1) * EH) : (const float*)nullptr;
        k_edge<<<BB * NN_, 256, 0, stream>>>(hT, pin, ef, adj, mode,
                                             gw1 + (size_t)i * 16576,
                                             g2t + (size_t)i * 16384, gb2 + i * DD,
                                             amean, amax);
        k_updp<<<BB * NN_ / 4, 256, 0, stream>>>(hin, amean, amax, nf,
                                                 uw1t + (size_t)i * 196608, ub1 + i * DD,
                                                 uw2t + (size_t)i * 65536, ub2 + i * DD,
                                                 lng + i * DD, lnb + i * DD, hout, out2sel,
                                                 g1tn, gb1n, pout, gpart, hT);
        float* t = hin; hin = hout; hout = t;
        t = pin; pin = pout; pout = t;
    }
    k_hmm<<<96, 256, 0, stream>>>(gpart, wsum, gd, qw, sw1, vw1, lpb, lpart, hpart);
    k_scr<<<BB * NN_ / 16, 256, 0, stream>>>(hin, kwt, kb, hpart, qb, sb1, vb1,
                                             sw2, sb2, vw2, vb2, out);
}

// Round 14
// 183.681 us; speedup vs baseline: 1.5528x; 1.0713x over previous
//
#include <hip/hip_runtime.h>
#include <hip/hip_bf16.h>
#include <math.h>

// Problem constants
#define BB 8
#define NN_ 128
#define DD 256
#define LL 64
#define EH 64
#define NG 3

typedef __attribute__((ext_vector_type(8))) short bs8;   // 8 bf16 (4 VGPR)
typedef __attribute__((ext_vector_type(4))) float f4;    // 4 f32

__device__ __forceinline__ short f2bf(float f) {
    __hip_bfloat16 h = __float2bfloat16(f);
    return *reinterpret_cast<short*>(&h);
}

__device__ __forceinline__ bs8 cvt8(const float* __restrict__ p) {
    bs8 r;
    #pragma unroll
    for (int i = 0; i < 8; ++i) r[i] = f2bf(p[i]);
    return r;
}

__device__ __forceinline__ float blockReduceSum(float v, float* sRed) {
    int tid = threadIdx.x;
    __syncthreads();
    sRed[tid] = v;
    __syncthreads();
    for (int s = 128; s > 0; s >>= 1) {
        if (tid < s) sRed[tid] += sRed[tid + s];
        __syncthreads();
    }
    return sRed[0];
}

// ---------------- unified prep: weight transposes + adj probe + layer-cost GEMM ----------------
// blocks 0..143 uw1, 144..191 uw2, 192..203 gw2, 204..215 gw1[:256], 216..231 kw,
// 232 adj-detect, 233..488 layer-cost conv+split-k GEMM
__global__ __launch_bounds__(256) void k_prep(
    const float* __restrict__ uw1, const float* __restrict__ uw2,
    const float* __restrict__ gw2, const float* __restrict__ gw1,
    const float* __restrict__ kw, const unsigned char* __restrict__ adj,
    const float* __restrict__ lc, const float* __restrict__ cw,
    const float* __restrict__ cb, const float* __restrict__ lpw,
    unsigned short* __restrict__ w1t, unsigned short* __restrict__ w2t,
    unsigned short* __restrict__ g2t, unsigned short* __restrict__ g1t,
    unsigned short* __restrict__ kwt, int* __restrict__ mode,
    float* __restrict__ lpart)
{
    const int blk = blockIdx.x, tid = threadIdx.x;
    if (blk == 232) {   // adj dtype probe: 0 = bool8, 1 = int32, 2 = float32
        __shared__ int sOff, sBig;
        if (tid == 0) { sOff = 0; sBig = 0; }
        __syncthreads();
        int off = 0, big = 0;
        #pragma unroll
        for (int k = 0; k < 4; ++k) {
            unsigned char v = adj[tid * 4 + k];
            if (v > 1) big = 1;
            if (k != 0 && v != 0) off = 1;
        }
        if (off) atomicOr(&sOff, 1);
        if (big) atomicOr(&sBig, 1);
        __syncthreads();
        if (tid == 0) mode[0] = sBig ? 2 : (sOff ? 0 : 1);
        return;
    }
    if (blk > 232) {    // layer-cost: conv + split-k GEMM -> lpart
        const int lb = blk - 233;
        const int b = lb >> 5, kseg = (lb >> 2) & 7, c4 = lb & 3;
        const int d = tid & 63, ss = tid >> 6;
        __shared__ float sC[LL];
        __shared__ float sV[124];
        __shared__ float sP[4][64];
        if (tid < LL) sC[tid] = lc[b * LL + tid];
        __syncthreads();
        if (tid < 124) {
            int idx = kseg * 124 + tid;
            int c = idx / 31, t = idx - c * 31;
            float a = cb[c];
            #pragma unroll
            for (int k = 0; k < 4; ++k) a += sC[2 * t + k] * cw[c * 4 + k];
            sV[tid] = fmaxf(a, 0.f);
        }
        __syncthreads();
        float acc = 0.f;
        for (int k = ss; k < 124; k += 4)
            acc += sV[k] * lpw[(size_t)(kseg * 124 + k) * DD + c4 * 64 + d];
        sP[ss][d] = acc;
        __syncthreads();
        if (ss == 0)
            lpart[(b * 32 + kseg * 4 + c4) * 64 + d] = sP[0][d] + sP[1][d] + sP[2][d] + sP[3][d];
        return;
    }
    // weight transposes
    const float* src; unsigned short* dst; int K, kt, dt, srcw = 256;
    if (blk < 144)      { int l = blk / 48, t = blk % 48; kt = t >> 2; dt = t & 3;
                          src = uw1 + (size_t)l * 196608; dst = w1t + (size_t)l * 196608; K = 768; }
    else if (blk < 192) { int x = blk - 144, l = x / 16, t = x % 16; kt = t >> 2; dt = t & 3;
                          src = uw2 + (size_t)l * 65536; dst = w2t + (size_t)l * 65536; K = 256; }
    else if (blk < 204) { int x = blk - 192, l = x >> 2; kt = 0; dt = x & 3;
                          src = gw2 + (size_t)l * 16384; dst = g2t + (size_t)l * 16384; K = 64; }
    else if (blk < 216) { int x = blk - 204, l = x >> 2; kt = x & 3; dt = 0; srcw = 64;
                          src = gw1 + (size_t)l * 16576; dst = g1t + (size_t)l * 16384; K = 256; }
    else                { int x = blk - 216; kt = x >> 2; dt = x & 3;
                          src = kw; dst = kwt; K = 256; }
    __shared__ float sT[64][65];
    #pragma unroll
    for (int q = 0; q < 16; ++q) {
        int idx = q * 256 + tid, kk = idx >> 6, dd = idx & 63;
        sT[kk][dd] = src[(size_t)(kt * 64 + kk) * srcw + dt * 64 + dd];
    }
    __syncthreads();
    const int d = tid >> 2, kc = (tid & 3) * 16;
    unsigned short* drow = dst + (size_t)(dt * 64 + d) * K + kt * 64 + kc;
    #pragma unroll
    for (int i = 0; i < 16; ++i) drow[i] = (unsigned short)f2bf(sT[kc + i][d]);
}

// ---------------- node projection + layer-0 pregate (16 rows/block, grid 64) ----------------
__global__ __launch_bounds__(256) void k_npp(
    const float* __restrict__ nf, const float* __restrict__ pnw,
    const float* __restrict__ pnb,
    const unsigned short* __restrict__ g1t, const float* __restrict__ gb1,
    float* __restrict__ h, float* __restrict__ preg)
{
    const int tid = threadIdx.x, blk = blockIdx.x;
    const int row0 = blk * 16;
    const int lane = tid & 63, w = tid >> 6;
    const int lcol = lane & 15, lrow = lane >> 4;
    __shared__ float sF[16][12];
    __shared__ float sH[16][260];    // +4 pad: rows land on distinct banks for MFMA A reads
    if (tid < 176) sF[tid / 11][tid % 11] = nf[(size_t)(row0 + tid / 11) * 11 + tid % 11];
    __syncthreads();
    float acc[16];
    {
        float bb = pnb[tid];
        #pragma unroll
        for (int rr = 0; rr < 16; ++rr) acc[rr] = bb;
    }
    #pragma unroll
    for (int f = 0; f < 11; ++f) {
        float wf = pnw[f * DD + tid];
        #pragma unroll
        for (int rr = 0; rr < 16; ++rr) acc[rr] += sF[rr][f] * wf;
    }
    #pragma unroll
    for (int rr = 0; rr < 16; ++rr) {
        sH[rr][tid] = acc[rr];
        h[(size_t)(row0 + rr) * DD + tid] = acc[rr];
    }
    __syncthreads();
    // pregate layer 0
    const unsigned short* bR = g1t + (size_t)(w * 16 + lcol) * 256;
    f4 a2 = {0.f, 0.f, 0.f, 0.f};
    #pragma unroll
    for (int ks = 0; ks < 8; ++ks) {
        int k0 = ks * 32 + lrow * 8;
        bs8 av = cvt8(&sH[lcol][k0]);
        bs8 bv = *(const bs8*)(bR + k0);
        a2 = __builtin_amdgcn_mfma_f32_16x16x32_bf16(av, bv, a2, 0, 0, 0);
    }
    const float gb = gb1[w * 16 + lcol];
    #pragma unroll
    for (int r = 0; r < 4; ++r)
        preg[(size_t)(row0 + lrow * 4 + r) * EH + w * 16 + lcol] = a2[r] + gb;
}

// ---------------- fused edge-gate (MFMA) + masked aggregation ----------------
__global__ __launch_bounds__(256) void k_edge(
    const float* __restrict__ h, const float* __restrict__ preg,
    const float* __restrict__ edge, const void* __restrict__ adj,
    const int* __restrict__ mode,
    const float* __restrict__ gw1,
    const unsigned short* __restrict__ g2t,
    const float* __restrict__ gb2,
    float* __restrict__ agg_mean, float* __restrict__ agg_max)
{
    const int tid = threadIdx.x;
    const int bi = blockIdx.x;
    const int b = bi >> 7;
    const int lane = tid & 63, w = tid >> 6;
    const int lrow = lane >> 4, lcol = lane & 15;
    const int md = mode[0];

    __shared__ __align__(16) unsigned int sHid[4096];
    __shared__ float sWe[192];
    __shared__ float sE[384];
    __shared__ unsigned long long sMask[2];

    if (tid < 192) sWe[tid] = gw1[16384 + tid];
    const float* eB = edge + (size_t)bi * 384;
    for (int idx = tid; idx < 384; idx += 256) sE[idx] = eB[idx];
    if (tid < 128) {
        int mv;
        if (md == 1)      mv = ((const int*)adj)[(size_t)bi * NN_ + tid] != 0;
        else if (md == 2) mv = ((const float*)adj)[(size_t)bi * NN_ + tid] != 0.f;
        else              mv = ((const unsigned char*)adj)[(size_t)bi * NN_ + tid] != 0;
        unsigned long long bal = __ballot(mv);
        if ((tid & 63) == 0) sMask[tid >> 6] = bal;
    }
    __syncthreads();

    const float* pB = preg + (size_t)b * NN_ * EH;
    #pragma unroll
    for (int q = 0; q < 16; ++q) {
        int idx = q * 256 + tid;
        int j = idx >> 5, p = idx & 31;
        float2 pv = *(const float2*)(pB + j * EH + 2 * p);
        float e0 = sE[j * 3], e1 = sE[j * 3 + 1], e2 = sE[j * 3 + 2];
        int t0 = 2 * p, t1 = t0 + 1;
        float v0 = fmaxf(pv.x + e0 * sWe[t0] + e1 * sWe[64 + t0] + e2 * sWe[128 + t0], 0.f);
        float v1 = fmaxf(pv.y + e0 * sWe[t1] + e1 * sWe[64 + t1] + e2 * sWe[128 + t1], 0.f);
        unsigned int pk = (unsigned int)(unsigned short)f2bf(v0) |
                          ((unsigned int)(unsigned short)f2bf(v1) << 16);
        sHid[j * 32 + (p ^ ((j & 7) << 2))] = pk;
    }
    __syncthreads();

    const unsigned long long m0 = sMask[0], m1 = sMask[1];
    const float cntf = (float)(__popcll(m0) + __popcll(m1));

    bs8 bfr[4][2];
    float bg[4];
    #pragma unroll
    for (int nt = 0; nt < 4; ++nt) {
        int d = w * 64 + nt * 16 + lcol;
        bg[nt] = gb2[d];
        #pragma unroll
        for (int ks = 0; ks < 2; ++ks) {
            int k0 = ks * 32 + lrow * 8;
            bfr[nt][ks] = *(const bs8*)(g2t + (size_t)d * 64 + k0);
        }
    }

    const float* hB = h + (size_t)b * NN_ * DD;
    float vs[4] = {0.f, 0.f, 0.f, 0.f};
    float vm[4] = {-INFINITY, -INFINITY, -INFINITY, -INFINITY};

    #pragma unroll
    for (int pp = 0; pp < 2; ++pp) {
        f4 acc[4][4] = {};
        #pragma unroll
        for (int ks = 0; ks < 2; ++ks) {
            bs8 afr[4];
            #pragma unroll
            for (int m = 0; m < 4; ++m) {
                int j = pp * 64 + m * 16 + lcol;
                int k0 = ks * 32 + lrow * 8;
                afr[m] = *(const bs8*)(sHid + (j * 32 + ((k0 >> 1) ^ ((j & 7) << 2))));
            }
            #pragma unroll
            for (int m = 0; m < 4; ++m)
                #pragma unroll
                for (int nt = 0; nt < 4; ++nt)
                    acc[m][nt] = __builtin_amdgcn_mfma_f32_16x16x32_bf16(
                        afr[m], bfr[nt][ks], acc[m][nt], 0, 0, 0);
        }
        const unsigned long long mw = pp ? m1 : m0;
        #pragma unroll
        for (int m = 0; m < 4; ++m) {
            #pragma unroll
            for (int nt = 0; nt < 4; ++nt) {
                int dnt = w * 64 + nt * 16 + lcol;
                #pragma unroll
                for (int r = 0; r < 4; ++r) {
                    int bit = m * 16 + lrow * 4 + r;
                    float x = acc[m][nt][r] + bg[nt];
                    float g = __builtin_amdgcn_rcpf(1.0f + __expf(-x));
                    float msg = g * hB[(pp * 64 + bit) * DD + dnt];
                    int on = (int)((mw >> bit) & 1ULL);
                    vs[nt] += on ? msg : 0.f;
                    vm[nt] = fmaxf(vm[nt], on ? msg : -INFINITY);
                }
            }
        }
    }

    #pragma unroll
    for (int nt = 0; nt < 4; ++nt) {
        float s = vs[nt];
        s += __shfl_xor(s, 16); s += __shfl_xor(s, 32);
        vs[nt] = s;
        float m = vm[nt];
        m = fmaxf(m, __shfl_xor(m, 16)); m = fmaxf(m, __shfl_xor(m, 32));
        vm[nt] = m;
    }
    const int g = lrow;
    float ssel = (g == 0) ? vs[0] : (g == 1) ? vs[1] : (g == 2) ? vs[2] : vs[3];
    float msel = (g == 0) ? vm[0] : (g == 1) ? vm[1] : (g == 2) ? vm[2] : vm[3];
    const int d = w * 64 + lane;
    agg_mean[(size_t)bi * DD + d] = ssel / fmaxf(cntf, 1.f);
    agg_max[(size_t)bi * DD + d] = (cntf > 0.f) ? msel : 0.f;
}

// ---------------- MFMA update MLP + residual + LN + next-layer pregate ----------------
__global__ __launch_bounds__(256) void k_updp(
    const float* __restrict__ h, const float* __restrict__ amean,
    const float* __restrict__ amax,
    const unsigned short* __restrict__ w1t,
    const float* __restrict__ ub1,
    const unsigned short* __restrict__ w2t,
    const float* __restrict__ ub2,
    const float* __restrict__ lng, const float* __restrict__ lnb,
    float* __restrict__ hout, float* __restrict__ out2,
    const unsigned short* __restrict__ g1tn, const float* __restrict__ gb1n,
    float* __restrict__ preg)
{
    const int tid = threadIdx.x;
    const int row0 = blockIdx.x * 4;
    const int lane = tid & 63, w = tid >> 6;
    const int lcol = lane & 15, lrow = lane >> 4;

    __shared__ __align__(16) unsigned int sX32[16 * 384];
    __shared__ __align__(16) unsigned short sH16[16 * 256];
    __shared__ float sRes[4][256];
    __shared__ float sOut[4][260];   // +4 pad for pregate A reads

    {
        const int j = w;
        const float* hR = h + (size_t)(row0 + j) * DD;
        const float* mR = amean + (size_t)(row0 + j) * DD;
        const float* xR = amax + (size_t)(row0 + j) * DD;
        #pragma unroll
        for (int q = 0; q < 6; ++q) {
            int p = lane + q * 64;
            int k = 2 * p;
            float2 v;
            if (k < 256)      { v = *(const float2*)(hR + k); sRes[j][k] = v.x; sRes[j][k + 1] = v.y; }
            else if (k < 512)   v = *(const float2*)(mR + (k - 256));
            else                v = *(const float2*)(xR + (k - 512));
            unsigned int pk = (unsigned int)(unsigned short)f2bf(v.x) |
                              ((unsigned int)(unsigned short)f2bf(v.y) << 16);
            sX32[j * 384 + (p ^ (j << 2))] = pk;
        }
    }
    __syncthreads();

    const char* sXb = (const char*)sX32;
    const unsigned short* w1r = w1t + (size_t)(w * 64 + lcol) * 768;
    f4 a0 = {0.f, 0.f, 0.f, 0.f}, a1 = a0, a2 = a0, a3 = a0;
    #pragma unroll 4
    for (int ks = 0; ks < 24; ++ks) {
        int k0 = ks * 32 + lrow * 8;
        bs8 av = *(const bs8*)(sXb + lcol * 1536 + ((((k0 >> 3) ^ (lcol & 7))) << 4));
        bs8 b0 = *(const bs8*)(w1r + k0);
        bs8 b1 = *(const bs8*)(w1r + 16 * 768 + k0);
        bs8 b2 = *(const bs8*)(w1r + 32 * 768 + k0);
        bs8 b3 = *(const bs8*)(w1r + 48 * 768 + k0);
        a0 = __builtin_amdgcn_mfma_f32_16x16x32_bf16(av, b0, a0, 0, 0, 0);
        a1 = __builtin_amdgcn_mfma_f32_16x16x32_bf16(av, b1, a1, 0, 0, 0);
        a2 = __builtin_amdgcn_mfma_f32_16x16x32_bf16(av, b2, a2, 0, 0, 0);
        a3 = __builtin_amdgcn_mfma_f32_16x16x32_bf16(av, b3, a3, 0, 0, 0);
    }
    if (lrow == 0) {
        #pragma unroll
        for (int nt = 0; nt < 4; ++nt) {
            int d = w * 64 + nt * 16 + lcol;
            float bb = ub1[d];
            f4 A = (nt == 0) ? a0 : (nt == 1) ? a1 : (nt == 2) ? a2 : a3;
            #pragma unroll
            for (int r = 0; r < 4; ++r) {
                float hv = fmaxf(A[r] + bb, 0.f);
                sH16[r * 256 + (d ^ (r << 3))] = (unsigned short)f2bf(hv);
            }
        }
    }
    __syncthreads();

    const unsigned short* w2r = w2t + (size_t)(w * 64 + lcol) * 256;
    f4 c0 = {0.f, 0.f, 0.f, 0.f}, c1 = c0, c2 = c0, c3 = c0;
    #pragma unroll
    for (int ks = 0; ks < 8; ++ks) {
        int k0 = ks * 32 + lrow * 8;
        bs8 av = *(const bs8*)((const char*)sH16 + lcol * 512 + ((((k0 >> 3) ^ (lcol & 7))) << 4));
        bs8 b0 = *(const bs8*)(w2r + k0);
        bs8 b1 = *(const bs8*)(w2r + 16 * 256 + k0);
        bs8 b2 = *(const bs8*)(w2r + 32 * 256 + k0);
        bs8 b3 = *(const bs8*)(w2r + 48 * 256 + k0);
        c0 = __builtin_amdgcn_mfma_f32_16x16x32_bf16(av, b0, c0, 0, 0, 0);
        c1 = __builtin_amdgcn_mfma_f32_16x16x32_bf16(av, b1, c1, 0, 0, 0);
        c2 = __builtin_amdgcn_mfma_f32_16x16x32_bf16(av, b2, c2, 0, 0, 0);
        c3 = __builtin_amdgcn_mfma_f32_16x16x32_bf16(av, b3, c3, 0, 0, 0);
    }
    if (lrow == 0) {
        #pragma unroll
        for (int nt = 0; nt < 4; ++nt) {
            int d = w * 64 + nt * 16 + lcol;
            float bb = ub2[d];
            f4 C = (nt == 0) ? c0 : (nt == 1) ? c1 : (nt == 2) ? c2 : c3;
            #pragma unroll
            for (int r = 0; r < 4; ++r)
                sOut[r][d] = C[r] + bb + sRes[r][d];
        }
    }
    __syncthreads();

    // LN: wave w handles row w (two-pass, shfl-only)
    float xv[4], s = 0.f;
    #pragma unroll
    for (int q = 0; q < 4; ++q) { xv[q] = sOut[w][lane + 64 * q]; s += xv[q]; }
    #pragma unroll
    for (int off = 1; off < 64; off <<= 1) s += __shfl_xor(s, off);
    const float mu = s * (1.f / DD);
    float s2 = 0.f;
    #pragma unroll
    for (int q = 0; q < 4; ++q) { float d = xv[q] - mu; s2 += d * d; }
    #pragma unroll
    for (int off = 1; off < 64; off <<= 1) s2 += __shfl_xor(s2, off);
    const float inv = rsqrtf(s2 * (1.f / DD) + 1e-5f);
    #pragma unroll
    for (int q = 0; q < 4; ++q) {
        int c = lane + 64 * q;
        float res = (xv[q] - mu) * inv * lng[c] + lnb[c];
        hout[(size_t)(row0 + w) * DD + c] = res;
        if (out2) out2[(size_t)(row0 + w) * DD + c] = res;
        sOut[w][c] = res;                    // post-LN into LDS for fused pregate
    }
    if (g1tn) {
        __syncthreads();
        const unsigned short* bR = g1tn + (size_t)(w * 16 + lcol) * 256;
        f4 p = {0.f, 0.f, 0.f, 0.f};
        #pragma unroll
        for (int ks = 0; ks < 8; ++ks) {
            int k0 = ks * 32 + lrow * 8;
            bs8 av = cvt8(&sOut[lcol & 3][k0]);   // A rows 4-15 duplicate 0-3 (unstored)
            bs8 bv = *(const bs8*)(bR + k0);
            p = __builtin_amdgcn_mfma_f32_16x16x32_bf16(av, bv, p, 0, 0, 0);
        }
        if (lrow == 0) {
            const float gb = gb1n[w * 16 + lcol];
            #pragma unroll
            for (int r = 0; r < 4; ++r)
                preg[(size_t)(row0 + r) * EH + w * 16 + lcol] = p[r] + gb;
        }
    }
}

// ---------------- graph embed ----------------
__global__ __launch_bounds__(256) void k_gembed(
    const float* __restrict__ nf, const float* __restrict__ h, float* __restrict__ ge)
{
    const int b = blockIdx.x, tid = threadIdx.x;
    __shared__ float sW[NN_];
    __shared__ float sRed[256];
    if (tid < NN_) {
        const float* p = nf + ((size_t)b * NN_ + tid) * 11;
        sW[tid] = p[0] * p[7];
    }
    __syncthreads();
    float part = (tid < NN_) ? sW[tid] : 0.f;
    float wsum = blockReduceSum(part, sRed);
    const float* hb = h + (size_t)b * NN_ * DD + tid;
    float a0 = 0.f, a1 = 0.f, a2 = 0.f, a3 = 0.f;
    for (int n = 0; n < 32; ++n) {
        a0 += sW[n]      * hb[(size_t)n * DD];
        a1 += sW[n + 32] * hb[(size_t)(n + 32) * DD];
        a2 += sW[n + 64] * hb[(size_t)(n + 64) * DD];
        a3 += sW[n + 96] * hb[(size_t)(n + 96) * DD];
    }
    ge[b * DD + tid] = (a0 + a1 + a2 + a3) / fmaxf(wsum, 1e-8f);
}

// ---------------- head GEMMs, all batches per weight load (lred fused in) ----------------
__global__ __launch_bounds__(256) void k_hmm(
    const float* __restrict__ ge, const float* __restrict__ gd,
    const float* __restrict__ qw, const float* __restrict__ sw1,
    const float* __restrict__ vw1,
    const float* __restrict__ lpb, const float* __restrict__ lpart,
    float* __restrict__ part)
{
    const int blk = blockIdx.x;
    const int m = blk >> 5, kseg = (blk >> 2) & 7, c4 = blk & 3;
    const int tid = threadIdx.x;
    const int d = tid & 63, ks = tid >> 6;
    const int K = (m == 1) ? 258 : 514;
    const int kc = (m == 1) ? 33 : 65;
    const int k0 = kseg * kc;
    const int klen = min(k0 + kc, K) - k0;
    __shared__ float sX[8 * 66];
    __shared__ float sP[4][8][64];
    for (int idx = tid; idx < 8 * kc; idx += 256) {
        int bb = idx / kc, kk = idx % kc, k = k0 + kk;
        float v = 0.f;
        if (k < K) {
            if (m == 1) v = (k < 256) ? ge[bb * DD + k] : gd[bb * 2 + (k - 256)];
            else if (k < 256) v = ge[bb * DD + k];
            else if (k < 512) {
                int e = k - 256;
                v = lpb[e];
                #pragma unroll
                for (int s = 0; s < 8; ++s)
                    v += lpart[(bb * 32 + s * 4 + (e >> 6)) * 64 + (e & 63)];
            } else v = gd[bb * 2 + (k - 512)];
        }
        sX[bb * 66 + kk] = v;
    }
    __syncthreads();
    const float* W = (m == 0) ? qw : (m == 1) ? sw1 : vw1;
    const int dg = c4 * 64 + d;
    float acc[8] = {0.f, 0.f, 0.f, 0.f, 0.f, 0.f, 0.f, 0.f};
    for (int kk = ks; kk < klen; kk += 4) {
        float wv = W[(size_t)(k0 + kk) * DD + dg];
        #pragma unroll
        for (int bb = 0; bb < 8; ++bb) acc[bb] += sX[bb * 66 + kk] * wv;
    }
    #pragma unroll
    for (int bb = 0; bb < 8; ++bb) sP[ks][bb][d] = acc[bb];
    __syncthreads();
    for (int idx = tid; idx < 8 * 64; idx += 256) {
        int bb = idx >> 6, dd = idx & 63;
        float sum = sP[0][bb][dd] + sP[1][bb][dd] + sP[2][bb][dd] + sP[3][bb][dd];
        part[((m * 8 + kseg) * 8 + bb) * DD + c4 * 64 + dd] = sum;
    }
}

// ---------------- MFMA device scores + query reduce + stop/value (fused tail) ----------------
__global__ __launch_bounds__(256) void k_scr(
    const float* __restrict__ h, const unsigned short* __restrict__ kwt,
    const float* __restrict__ kb, const float* __restrict__ hpart,
    const float* __restrict__ qb,
    const float* __restrict__ sb1, const float* __restrict__ vb1,
    const float* __restrict__ sw2, const float* __restrict__ sb2,
    const float* __restrict__ vw2, const float* __restrict__ vb2,
    float* __restrict__ out)
{
    const int tid = threadIdx.x, blk = blockIdx.x;
    const int row0 = blk * 16, b = blk >> 3, chunk = blk & 7;
    const int lane = tid & 63, w = tid >> 6;
    const int lcol = lane & 15, lrow = lane >> 4;
    __shared__ float sQ[256];
    __shared__ float sPart[4][16];
    __shared__ float sRed[256];
    // query for this batch (replicated reduce)
    {
        float qv = qb[tid];
        #pragma unroll
        for (int kseg = 0; kseg < 8; ++kseg)
            qv += hpart[(size_t)(kseg * 8 + b) * DD + tid];
        sQ[tid] = qv;
    }
    __syncthreads();
    const float* aR = h + (size_t)(row0 + lcol) * DD;
    f4 acc[4] = {};
    #pragma unroll
    for (int ks = 0; ks < 8; ++ks) {
        int k0 = ks * 32 + lrow * 8;
        bs8 av = cvt8(aR + k0);
        #pragma unroll
        for (int nt = 0; nt < 4; ++nt) {
            bs8 bv = *(const bs8*)(kwt + (size_t)(w * 64 + nt * 16 + lcol) * 256 + k0);
            acc[nt] = __builtin_amdgcn_mfma_f32_16x16x32_bf16(av, bv, acc[nt], 0, 0, 0);
        }
    }
    float part[4] = {0.f, 0.f, 0.f, 0.f};
    #pragma unroll
    for (int nt = 0; nt < 4; ++nt) {
        int col = w * 64 + nt * 16 + lcol;
        float q = sQ[col], kv = kb[col];
        #pragma unroll
        for (int r = 0; r < 4; ++r) part[r] += (acc[nt][r] + kv) * q;
    }
    #pragma unroll
    for (int r = 0; r < 4; ++r) {
        float s = part[r];
        s += __shfl_xor(s, 1); s += __shfl_xor(s, 2);
        s += __shfl_xor(s, 4); s += __shfl_xor(s, 8);
        part[r] = s;
    }
    if (lcol == 0) {
        #pragma unroll
        for (int r = 0; r < 4; ++r) sPart[w][lrow * 4 + r] = part[r];
    }
    __syncthreads();
    if (tid < 16) {
        float s = sPart[0][tid] + sPart[1][tid] + sPart[2][tid] + sPart[3][tid];
        out[b * 129 + (row0 & (NN_ - 1)) + tid] = s * 0.0625f;
    }
    // stop/value heads: one block per batch (chunk 0)
    if (chunk == 0) {
        float s = sb1[tid], v = vb1[tid];
        #pragma unroll
        for (int kseg = 0; kseg < 8; ++kseg) {
            s += hpart[(size_t)((8 + kseg) * 8 + b) * DD + tid];
            v += hpart[(size_t)((16 + kseg) * 8 + b) * DD + tid];
        }
        s = fmaxf(s, 0.f); v = fmaxf(v, 0.f);
        float stop = blockReduceSum(s * sw2[tid], sRed);
        float val  = blockReduceSum(v * vw2[tid], sRed);
        if (tid == 0) {
            out[b * 129 + 128] = stop + sb2[0];
            out[1032 + b] = val + vb2[0];
        }
    }
}

extern "C" void kernel_launch(void* const* d_in, const int* in_sizes, int n_in,
                              void* d_out, int out_size, void* d_ws, size_t ws_size,
                              hipStream_t stream) {
    (void)in_sizes; (void)n_in; (void)out_size; (void)ws_size;
    const float* nf  = (const float*)d_in[0];
    const float* ef  = (const float*)d_in[1];
    const void*  adj = d_in[2];
    const float* lc  = (const float*)d_in[3];
    const float* gd  = (const float*)d_in[4];
    const float* pnw = (const float*)d_in[5];
    const float* pnb = (const float*)d_in[6];
    const float* gw1 = (const float*)d_in[7];
    const float* gb1 = (const float*)d_in[8];
    const float* gw2 = (const float*)d_in[9];
    const float* gb2 = (const float*)d_in[10];
    const float* uw1 = (const float*)d_in[11];
    const float* ub1 = (const float*)d_in[12];
    const float* uw2 = (const float*)d_in[13];
    const float* ub2 = (const float*)d_in[14];
    const float* lng = (const float*)d_in[15];
    const float* lnb = (const float*)d_in[16];
    const float* cw  = (const float*)d_in[17];
    const float* cb  = (const float*)d_in[18];
    const float* lpw = (const float*)d_in[19];
    const float* lpb = (const float*)d_in[20];
    const float* qw  = (const float*)d_in[21];
    const float* qb  = (const float*)d_in[22];
    const float* kw  = (const float*)d_in[23];
    const float* kb  = (const float*)d_in[24];
    const float* sw1 = (const float*)d_in[25];
    const float* sb1 = (const float*)d_in[26];
    const float* sw2 = (const float*)d_in[27];
    const float* sb2 = (const float*)d_in[28];
    const float* vw1 = (const float*)d_in[29];
    const float* vb1 = (const float*)d_in[30];
    const float* vw2 = (const float*)d_in[31];
    const float* vb2 = (const float*)d_in[32];

    float* ws = (float*)d_ws;
    float* h     = ws;                         // 262144
    float* preg  = ws + 262144;                // 65536
    float* amean = ws + 327680;                // 262144
    float* amax  = ws + 589824;                // 262144
    float* ge    = ws + 851968;                // 2048
    float* lpart = ws + 856064;                // 16384
    float* hpart = ws + 872448;                // 49152
    int*   mode  = (int*)(ws + 921600);        // 1 (pad to 921604)
    unsigned short* uw1t = (unsigned short*)(ws + 921604);    // 589824 shorts
    unsigned short* uw2t = (unsigned short*)(ws + 1216516);   // 196608 shorts
    unsigned short* g2t  = (unsigned short*)(ws + 1314820);   // 49152 shorts
    unsigned short* g1t  = (unsigned short*)(ws + 1339396);   // 49152 shorts
    unsigned short* kwt  = (unsigned short*)(ws + 1363972);   // 65536 shorts
    float* out   = (float*)d_out;

    k_prep<<<489, 256, 0, stream>>>(uw1, uw2, gw2, gw1, kw,
                                    (const unsigned char*)adj,
                                    lc, cw, cb, lpw,
                                    uw1t, uw2t, g2t, g1t, kwt, mode, lpart);
    k_npp<<<BB * NN_ / 16, 256, 0, stream>>>(nf, pnw, pnb, g1t, gb1, h, preg);
    for (int i = 0; i < NG; ++i) {
        const float* gw1i = gw1 + (size_t)i * 259 * EH;
        float* out2sel = (i == NG - 1) ? (out + 1040) : (float*)nullptr;
        const unsigned short* g1tn = (i < NG - 1) ? (g1t + (size_t)(i + 1) * 16384)
                                                  : (const unsigned short*)nullptr;
        const float* gb1n = (i < NG - 1) ? (gb1 + (i + 1) * EH) : (const float*)nullptr;
        k_edge<<<BB * NN_, 256, 0, stream>>>(h, preg, ef, adj, mode, gw1i,
                                             g2t + (size_t)i * 16384,
                                             gb2 + i * DD, amean, amax);
        k_updp<<<BB * NN_ / 4, 256, 0, stream>>>(h, amean, amax,
                                                 uw1t + (size_t)i * 196608, ub1 + i * DD,
                                                 uw2t + (size_t)i * 65536, ub2 + i * DD,
                                                 lng + i * DD, lnb + i * DD, h, out2sel,
                                                 g1tn, gb1n, preg);
    }
    k_gembed<<<BB, 256, 0, stream>>>(nf, h, ge);
    k_hmm<<<96, 256, 0, stream>>>(ge, gd, qw, sw1, vw1, lpb, lpart, hpart);
    k_scr<<<BB * NN_ / 16, 256, 0, stream>>>(h, kwt, kb, hpart, qb, sb1, vb1,
                                             sw2, sb2, vw2, vb2, out);
}